// Round 1
// baseline (1396.080 us; speedup 1.0000x reference)
//
#include <hip/hip_runtime.h>
#include <cstdint>
#include <cstddef>

#define Hn 8192
#define Nn 4096
#define Cn 128
#define Tt 256
#define PWw 8

// stdp(dt) = dt>=0 ? 0.01*exp(-dt/20) : -0.01*exp(dt/20)
__device__ __forceinline__ float stdp_f(float dt){
    const float K = 0.07213475204444817f; // log2(e)/20
    float a = fabsf(dt);
    float e = exp2f(-a * K);
    return dt >= 0.f ? 0.01f * e : -0.01f * e;
}

// ---------------- k_prep: start times + deterministic counting sort ----------------
__global__ __launch_bounds__(256) void k_prep(const float* __restrict__ image,
        int* __restrict__ start, int* __restrict__ boff, int* __restrict__ sidx){
    __shared__ int s_start[Nn];
    __shared__ int s_cnt[Tt];
    __shared__ int s_off[Tt + 1];
    int tid = threadIdx.x;
    for (int i = tid; i < Nn; i += 256){
        int s = (int)floorf(__fmul_rn(256.f, image[i]));
        s_start[i] = s; start[i] = s;
    }
    if (tid < Tt) s_cnt[tid] = 0;
    __syncthreads();
    for (int i = tid; i < Nn; i += 256) atomicAdd(&s_cnt[s_start[i]], 1);
    __syncthreads();
    if (tid == 0){
        int acc = 0;
        for (int t = 0; t < Tt; ++t){ s_off[t] = acc; acc += s_cnt[t]; }
        s_off[Tt] = acc;
    }
    __syncthreads();
    // thread t gathers its bucket's indices in ascending order (deterministic)
    {
        int p = s_off[tid];
        for (int i = 0; i < Nn; ++i)
            if (s_start[i] == tid) sidx[p++] = i;
        boff[tid] = s_off[tid];
        if (tid == 0) boff[Tt] = s_off[Tt];
    }
}

// ---------------- k_gbuckets: G_T[h][t] = sum_{i in bucket t} W1[h][i] ----------------
__global__ __launch_bounds__(256) void k_gbuckets(const float* __restrict__ W1,
        const int* __restrict__ boff, const int* __restrict__ sidx,
        float* __restrict__ G_T){
    __shared__ float rows[4][Nn]; // 64 KB
    int tid = threadIdx.x;
    int h0 = blockIdx.x * 4;
    for (int r = 0; r < 4; ++r){
        const float4* src = (const float4*)(W1 + (size_t)(h0 + r) * Nn);
        float4* dst = (float4*)rows[r];
        for (int j = tid; j < Nn / 4; j += 256) dst[j] = src[j];
    }
    __syncthreads();
    int t = tid;
    int b0 = boff[t], b1 = boff[t + 1];
    float s0 = 0.f, s1 = 0.f, s2 = 0.f, s3 = 0.f;
    for (int k = b0; k < b1; ++k){
        int i = sidx[k];
        s0 += rows[0][i]; s1 += rows[1][i]; s2 += rows[2][i]; s3 += rows[3][i];
    }
    G_T[(size_t)(h0 + 0) * Tt + t] = s0;
    G_T[(size_t)(h0 + 1) * Tt + t] = s1;
    G_T[(size_t)(h0 + 2) * Tt + t] = s2;
    G_T[(size_t)(h0 + 3) * Tt + t] = s3;
}

// ---------------- k_c1: c1[t][h] = sum_{tau=max(0,t-7)..t} G_T[h][tau] ----------------
__global__ __launch_bounds__(256) void k_c1(const float* __restrict__ G_T,
                                            float* __restrict__ c1){
    __shared__ float tile[32][Tt + 1];
    int tid = threadIdx.x;
    int h0 = blockIdx.x * 32;
    for (int r = 0; r < 32; ++r) tile[r][tid] = G_T[(size_t)(h0 + r) * Tt + tid];
    __syncthreads();
    int hs = tid & 31, ts = tid >> 5;
    for (int tb = 0; tb < 32; ++tb){
        int t = tb * 8 + ts;
        int lo = (t - 7 < 0) ? 0 : t - 7;
        float s = 0.f;
        for (int u = lo; u <= t; ++u) s += tile[hs][u];
        c1[(size_t)t * Hn + h0 + hs] = s;
    }
}

// ---------------- k_sim1: layer-1 LIF + WTA, single block, state in registers ----------------
__global__ __launch_bounds__(1024) void k_sim1(const float* __restrict__ c1,
        const float* __restrict__ thr1, float* __restrict__ r1pre,
        float* __restrict__ o_r1, int* __restrict__ j1, int* __restrict__ fired){
    int tid = threadIdx.x;
    int lane = tid & 63, w = tid >> 6;
    int hbase = tid * 8;
    float mem[8], th[8], r1p[8];
    for (int k = 0; k < 8; ++k){ mem[k] = 0.f; r1p[k] = 0.f; th[k] = thr1[hbase + k]; }
    __shared__ float s_wv[2][16];
    __shared__ float s_wt[2][16];
    __shared__ int   s_wi[2][16];
    __shared__ int   s_bj[2];
    __shared__ int   s_bf[2];
    __shared__ int   s_j1[Tt];
    __shared__ int   s_f[Tt];

    float4 A0, A1, B0, B1;
    {
        const float4* p0 = (const float4*)(c1) + tid * 2;
        A0 = p0[0]; A1 = p0[1];
        const float4* p1 = (const float4*)(c1 + (size_t)Hn) + tid * 2;
        B0 = p1[0]; B1 = p1[1];
    }
    for (int t = 0; t < Tt; ++t){
        int tn = (t + 2 < Tt) ? t + 2 : Tt - 1;
        const float4* pn = (const float4*)(c1 + (size_t)tn * Hn) + tid * 2;
        float4 C0 = pn[0], C1 = pn[1];

        float cv[8] = {A0.x, A0.y, A0.z, A0.w, A1.x, A1.y, A1.z, A1.w};
        float bv = -3.4e38f, bth = 0.f;
        int bi = 0x7fffffff;
        for (int k = 0; k < 8; ++k){
            mem[k] = __fadd_rn(__fmul_rn(0.9f, mem[k]), cv[k]); // BETA1
            if (mem[k] > bv){ bv = mem[k]; bth = th[k]; bi = hbase + k; }
        }
        // wave argmax (tie -> lower index, matches jnp.argmax first-max)
        for (int off = 32; off >= 1; off >>= 1){
            float ov = __shfl_down(bv, off);
            float ot = __shfl_down(bth, off);
            int   oi = __shfl_down(bi, off);
            if (ov > bv || (ov == bv && oi < bi)){ bv = ov; bth = ot; bi = oi; }
        }
        int p = t & 1;
        if (lane == 0){ s_wv[p][w] = bv; s_wt[p][w] = bth; s_wi[p][w] = bi; }
        __syncthreads();
        if (tid < 64){
            float v  = (tid < 16) ? s_wv[p][tid] : -3.4e38f;
            float vt = (tid < 16) ? s_wt[p][tid] : 0.f;
            int   vi = (tid < 16) ? s_wi[p][tid] : 0x7fffffff;
            for (int off = 8; off >= 1; off >>= 1){
                float ov = __shfl_down(v, off);
                float ot = __shfl_down(vt, off);
                int   oi = __shfl_down(vi, off);
                if (ov > v || (ov == v && oi < vi)){ v = ov; vt = ot; vi = oi; }
            }
            if (tid == 0){
                int f = (v > vt) ? 1 : 0;
                s_bj[p] = vi; s_bf[p] = f;
                s_j1[t] = vi; s_f[t] = f;
            }
        }
        __syncthreads();
        int bj = s_bj[p], bf = s_bf[p];
        if (bf && (bj >> 3) == tid){
            int k = bj & 7;
            mem[k] = 0.f;                       // reset-to-zero (WTA winner)
            if (r1p[k] == 0.f) r1p[k] = (float)(t + 1);
        }
        for (int k = 0; k < 8; ++k){
            float x = __fadd_rn(__fsub_rn(th[k], 0.05f),
                                (bf && (hbase + k) == bj) ? 5.0f : 0.0f);
            x = fmaxf(x, 150.0f); x = fminf(x, 400.0f);
            th[k] = x;
        }
        A0 = B0; A1 = B1; B0 = C0; B1 = C1;
    }
    for (int k = 0; k < 8; ++k){
        float rp = r1p[k];
        r1pre[hbase + k] = rp;
        o_r1[hbase + k] = (rp == 0.f) ? 256.f : rp;
    }
    for (int i = tid; i < Tt; i += 1024){ j1[i] = s_j1[i]; fired[i] = s_f[i]; }
}

// ---------------- k_w2gather: W2cols[t][n] = fired[t] ? W2[n][j1[t]] : 0 ----------------
__global__ __launch_bounds__(256) void k_w2gather(const float* __restrict__ W2,
        const int* __restrict__ j1, const int* __restrict__ fired,
        float* __restrict__ W2cols){
    int t = blockIdx.x, tid = threadIdx.x;
    float* dst = W2cols + (size_t)t * Nn;
    if (!fired[t]){
        for (int n = tid; n < Nn; n += 256) dst[n] = 0.f;
    } else {
        int col = j1[t];
        for (int n = tid; n < Nn; n += 256) dst[n] = W2[(size_t)n * Hn + col];
    }
}

// ---------------- k_w3t: W3T[n][c] = W3[c][n] ----------------
__global__ __launch_bounds__(256) void k_w3t(const float* __restrict__ W3,
                                             float* __restrict__ W3T){
    __shared__ float tl[64][65];
    int bx = blockIdx.x & 63, by = blockIdx.x >> 6;
    int n0 = bx * 64, c0 = by * 64;
    int tid = threadIdx.x;
    for (int e = tid; e < 64 * 64; e += 256){
        int r = e >> 6, cc = e & 63;
        tl[r][cc] = W3[(size_t)(c0 + r) * Nn + n0 + cc];
    }
    __syncthreads();
    for (int e = tid; e < 64 * 64; e += 256){
        int rn = e >> 6, cc = e & 63;
        W3T[(size_t)(n0 + rn) * Cn + c0 + cc] = tl[cc][rn];
    }
}

// ---------------- k_sim2: layers 2+3, single block ----------------
__global__ __launch_bounds__(1024) void k_sim2(const float* __restrict__ W2cols,
        const float* __restrict__ W3T, const float* __restrict__ thr2,
        const float* __restrict__ thr3, float* __restrict__ o_r2,
        float* __restrict__ o_r3){
    int tid = threadIdx.x, lane = tid & 63, w = tid >> 6;
    int nbase = tid * 4;
    float mem2[4] = {0.f, 0.f, 0.f, 0.f}, r2p[4] = {0.f, 0.f, 0.f, 0.f};
    float tv[4];
    for (int k = 0; k < 4; ++k) tv[k] = thr2[nbase + k];
    __shared__ int   s_list[Nn];
    __shared__ float s_part[8][128];
    __shared__ float s_mem3[Cn], s_th3[Cn], s_r3[Cn];
    __shared__ int   s_wtot[16];
    __shared__ int   s_woff[16];
    __shared__ int   s_cnt;
    __shared__ int   s_b3j, s_b3f;
    if (tid < Cn){ s_mem3[tid] = 0.f; s_th3[tid] = thr3[tid]; s_r3[tid] = 0.f; }
    float4 A = ((const float4*)W2cols)[tid];
    float4 B = ((const float4*)(W2cols + Nn))[tid];
    __syncthreads();
    for (int t = 0; t < Tt; ++t){
        int tn = (t + 2 < Tt) ? t + 2 : Tt - 1;
        float4 Cld = ((const float4*)(W2cols + (size_t)tn * Nn))[tid];
        float u[4] = {A.x, A.y, A.z, A.w};
        int bits = 0;
        for (int k = 0; k < 4; ++k){
            float m = __fadd_rn(__fmul_rn(0.8f, mem2[k]), u[k]); // BETA2
            if (m > tv[k]){
                bits |= (1 << k);
                m = __fsub_rn(m, tv[k]);                 // reset-by-subtract
                if (r2p[k] == 0.f) r2p[k] = (float)(t + 1);
            }
            mem2[k] = m;
        }
        int cnt = __popc((unsigned)bits);
        int inc = cnt;
        for (int off = 1; off <= 32; off <<= 1){
            int v = __shfl_up(inc, off);
            if (lane >= off) inc += v;
        }
        int exc = inc - cnt;
        if (lane == 63) s_wtot[w] = inc;
        __syncthreads();
        if (tid == 0){
            int acc = 0;
            for (int q = 0; q < 16; ++q){ s_woff[q] = acc; acc += s_wtot[q]; }
            s_cnt = acc;
        }
        __syncthreads();
        int base = s_woff[w] + exc;
        for (int k = 0; k < 4; ++k)
            if ((bits >> k) & 1) s_list[base++] = nbase + k; // ascending n, deterministic
        __syncthreads();
        int CNT = s_cnt;
        int g = tid >> 7, c = tid & 127;
        float ps = 0.f;
        for (int e = g; e < CNT; e += 8) ps += W3T[(size_t)s_list[e] * Cn + c];
        s_part[g][c] = ps;
        __syncthreads();
        if (tid < Cn){
            float s = 0.f;
            for (int q = 0; q < 8; ++q) s += s_part[q][tid];
            s_mem3[tid] = __fadd_rn(__fmul_rn(0.9f, s_mem3[tid]), s); // BETA3
        }
        __syncthreads();
        if (tid < 64){
            float v0 = s_mem3[tid], v1 = s_mem3[tid + 64];
            float bv, bth; int bi;
            if (v1 > v0){ bv = v1; bth = s_th3[tid + 64]; bi = tid + 64; }
            else        { bv = v0; bth = s_th3[tid];      bi = tid; }
            for (int off = 32; off >= 1; off >>= 1){
                float ov = __shfl_down(bv, off);
                float ot = __shfl_down(bth, off);
                int   oi = __shfl_down(bi, off);
                if (ov > bv || (ov == bv && oi < bi)){ bv = ov; bth = ot; bi = oi; }
            }
            if (tid == 0){ s_b3j = bi; s_b3f = (bv > bth) ? 1 : 0; }
        }
        __syncthreads();
        int b3f = s_b3f, b3j = s_b3j;
        if (tid < Cn){
            float m3 = s_mem3[tid];
            if (b3f) m3 = 0.f;                 // zeroed after any spike
            s_mem3[tid] = m3;
            float x = __fadd_rn(__fsub_rn(s_th3[tid], 0.05f),
                                (b3f && tid == b3j) ? 5.0f : 0.0f);
            x = fmaxf(x, 50.f); x = fminf(x, 200.f);
            s_th3[tid] = x;
            if (b3f && tid == b3j && s_r3[tid] == 0.f) s_r3[tid] = (float)(t + 1);
        }
        __syncthreads();
        A = B; B = Cld;
    }
    for (int k = 0; k < 4; ++k){
        float rp = r2p[k];
        o_r2[nbase + k] = (rp == 0.f) ? 256.f : rp;
    }
    if (tid < Cn) o_r3[tid] = (s_r3[tid] == 0.f) ? 256.f : s_r3[tid];
}

// ---------------- k_scalars: zeta, rho, error, error_scalar ----------------
__global__ __launch_bounds__(1024) void k_scalars(const float* __restrict__ image,
        const float* __restrict__ r1pre, const float* __restrict__ o_r1,
        const float* __restrict__ o_r2, float* __restrict__ zeta,
        float* __restrict__ rho, float* __restrict__ o_err,
        float* __restrict__ o_es){
    int tid = threadIdx.x;
    for (int h = tid; h < Hn; h += 1024){
        float r1f = o_r1[h];
        float mask = (r1pre[h] != 0.f) ? 1.f : 0.f;
        zeta[h] = __fmul_rn(__fmul_rn(__fsub_rn(256.f, r1f), mask), 0.00390625f);
    }
    float acc = 0.f;
    for (int n = tid; n < Nn; n += 1024){
        float img = __fmul_rn(256.f, image[n]);
        float r2f = o_r2[n];
        float e = __fmul_rn(__fsub_rn(img, __fsub_rn(r2f, 4.0f)), 0.00390625f);
        o_err[n] = e;
        rho[n] = __fadd_rn(__fmul_rn(__fsub_rn(__fsub_rn(r2f, 4.0f), img), 0.00390625f), 0.15f);
        acc = __fadd_rn(acc, __fmul_rn(e, e));
    }
    __shared__ float red[16];
    for (int off = 32; off >= 1; off >>= 1) acc += __shfl_down(acc, off);
    int lane = tid & 63, w = tid >> 6;
    if (lane == 0) red[w] = acc;
    __syncthreads();
    if (tid == 0){
        float s = 0.f;
        for (int q = 0; q < 16; ++q) s += red[q];
        *o_es = s;
    }
}

// ---------------- STDP weight-update kernels ----------------
__global__ __launch_bounds__(256) void k_w1new(const float* __restrict__ W1,
        const float* __restrict__ image, const float* __restrict__ r1pre,
        const float* __restrict__ o_r1, float* __restrict__ o_W1){
    int h = blockIdx.x, tid = threadIdx.x;
    float r1f = o_r1[h];
    bool mask = (r1pre[h] != 0.f);
    const float* src = W1 + (size_t)h * Nn;
    float* dst = o_W1 + (size_t)h * Nn;
    if (!mask){
        for (int i = tid; i < Nn; i += 256)
            dst[i] = __fadd_rn(src[i], 0.01f);       // stdp(0) = A_P
    } else {
        for (int i = tid; i < Nn; i += 256){
            float img = __fmul_rn(256.f, image[i]);
            float dt = __fsub_rn(r1f, img);
            dst[i] = __fadd_rn(src[i], stdp_f(dt));
        }
    }
}

__global__ __launch_bounds__(256) void k_w2new(const float* __restrict__ W2,
        const float* __restrict__ o_r1, const float* __restrict__ o_r2,
        const float* __restrict__ zeta, const float* __restrict__ rho,
        float* __restrict__ o_W2){
    int n = blockIdx.x, tid = threadIdx.x;
    float r2f = o_r2[n], rh = rho[n];
    const float* src = W2 + (size_t)n * Hn;
    float* dst = o_W2 + (size_t)n * Hn;
    for (int hh = tid; hh < Hn; hh += 256){
        float dt = __fsub_rn(r2f, o_r1[hh]);
        float rz = __fmul_rn(rh, zeta[hh]);
        float v = __fadd_rn(src[hh], __fmul_rn(stdp_f(dt), rz));
        v = fmaxf(v, 0.f); v = fminf(v, 1.f);
        dst[hh] = v;
    }
}

__global__ __launch_bounds__(256) void k_w3new(const float* __restrict__ W3,
        const float* __restrict__ o_r2, const float* __restrict__ o_r3,
        float* __restrict__ o_W3){
    int c = blockIdx.x, tid = threadIdx.x;
    float r3f = o_r3[c];
    const float* src = W3 + (size_t)c * Nn;
    float* dst = o_W3 + (size_t)c * Nn;
    for (int i = tid; i < Nn; i += 256){
        float dt = __fsub_rn(r3f, o_r2[i]);
        dst[i] = __fadd_rn(src[i], stdp_f(dt));
    }
}

extern "C" void kernel_launch(void* const* d_in, const int* in_sizes, int n_in,
                              void* d_out, int out_size, void* d_ws, size_t ws_size,
                              hipStream_t stream){
    const float* image = (const float*)d_in[0];
    const float* W1   = (const float*)d_in[1];
    const float* W2   = (const float*)d_in[2];
    const float* W3   = (const float*)d_in[3];
    const float* thr1 = (const float*)d_in[4];
    const float* thr2 = (const float*)d_in[5];
    const float* thr3 = (const float*)d_in[6];

    float* out  = (float*)d_out;
    float* o_err = out;                       // [4096]
    float* o_es  = out + 4096;                // [1]
    float* o_r1  = out + 4097;                // [8192]
    float* o_r2  = out + 12289;               // [4096]
    float* o_r3  = out + 16385;               // [128]
    float* o_W1  = out + 16513;               // [8192*4096]
    float* o_W2  = o_W1 + (size_t)Hn * Nn;    // [4096*8192]
    float* o_W3  = o_W2 + (size_t)Nn * Hn;    // [128*4096]

    float* ws = (float*)d_ws;
    float* G_T    = ws;                            // H*T
    float* c1     = G_T + (size_t)Hn * Tt;         // T*H
    float* W2cols = c1 + (size_t)Tt * Hn;          // T*N
    float* W3T    = W2cols + (size_t)Tt * Nn;      // N*C
    float* r1pre  = W3T + (size_t)Nn * Cn;         // H
    float* zeta   = r1pre + Hn;                    // H
    float* rho    = zeta + Hn;                     // N
    int* start = (int*)(rho + Nn);                 // N
    int* boff  = start + Nn;                       // T+1
    int* sidx  = boff + (Tt + 1);                  // N
    int* j1    = sidx + Nn;                        // T
    int* fired = j1 + Tt;                          // T

    k_prep<<<1, 256, 0, stream>>>(image, start, boff, sidx);
    k_gbuckets<<<Hn / 4, 256, 0, stream>>>(W1, boff, sidx, G_T);
    k_c1<<<Hn / 32, 256, 0, stream>>>(G_T, c1);
    k_sim1<<<1, 1024, 0, stream>>>(c1, thr1, r1pre, o_r1, j1, fired);
    k_w2gather<<<Tt, 256, 0, stream>>>(W2, j1, fired, W2cols);
    k_w3t<<<128, 256, 0, stream>>>(W3, W3T);
    k_sim2<<<1, 1024, 0, stream>>>(W2cols, W3T, thr2, thr3, o_r2, o_r3);
    k_scalars<<<1, 1024, 0, stream>>>(image, r1pre, o_r1, o_r2, zeta, rho, o_err, o_es);
    k_w1new<<<Hn, 256, 0, stream>>>(W1, image, r1pre, o_r1, o_W1);
    k_w2new<<<Nn, 256, 0, stream>>>(W2, o_r1, o_r2, zeta, rho, o_W2);
    k_w3new<<<Cn, 256, 0, stream>>>(W3, o_r2, o_r3, o_W3);
}

// Round 2
// 1073.514 us; speedup vs baseline: 1.3005x; 1.3005x over previous
//
#include <hip/hip_runtime.h>
#include <cstdint>
#include <cstddef>

#define Hn 8192
#define Nn 4096
#define Cn 128
#define Tt 256
#define PWw 8

// stdp(dt) = dt>=0 ? 0.01*exp(-dt/20) : -0.01*exp(dt/20)
__device__ __forceinline__ float stdp_f(float dt){
    const float K = 0.07213475204444817f; // log2(e)/20
    float a = fabsf(dt);
    float e = exp2f(-a * K);
    return dt >= 0.f ? 0.01f * e : -0.01f * e;
}

// raw barrier: publish LDS writes, do NOT drain vmcnt (keeps prefetch in flight)
__device__ __forceinline__ void bar_lgkm(){
    asm volatile("s_waitcnt lgkmcnt(0)" ::: "memory");
    __builtin_amdgcn_s_barrier();
    __builtin_amdgcn_sched_barrier(0);
}

// ---------------- k_prep: start times + deterministic counting sort ----------------
__global__ __launch_bounds__(256) void k_prep(const float* __restrict__ image,
        int* __restrict__ start, int* __restrict__ boff, int* __restrict__ sidx){
    __shared__ int s_start[Nn];
    __shared__ int s_cnt[Tt];
    __shared__ int s_off[Tt + 1];
    int tid = threadIdx.x;
    for (int i = tid; i < Nn; i += 256){
        int s = (int)floorf(__fmul_rn(256.f, image[i]));
        s_start[i] = s; start[i] = s;
    }
    if (tid < Tt) s_cnt[tid] = 0;
    __syncthreads();
    for (int i = tid; i < Nn; i += 256) atomicAdd(&s_cnt[s_start[i]], 1);
    __syncthreads();
    if (tid == 0){
        int acc = 0;
        for (int t = 0; t < Tt; ++t){ s_off[t] = acc; acc += s_cnt[t]; }
        s_off[Tt] = acc;
    }
    __syncthreads();
    {
        int p = s_off[tid];
        for (int i = 0; i < Nn; ++i)
            if (s_start[i] == tid) sidx[p++] = i;
        boff[tid] = s_off[tid];
        if (tid == 0) boff[Tt] = s_off[Tt];
    }
}

// ---------------- k_gbuckets: G_T[h][t] = sum_{i in bucket t} W1[h][i] ----------------
__global__ __launch_bounds__(256) void k_gbuckets(const float* __restrict__ W1,
        const int* __restrict__ boff, const int* __restrict__ sidx,
        float* __restrict__ G_T){
    __shared__ float rows[4][Nn]; // 64 KB
    int tid = threadIdx.x;
    int h0 = blockIdx.x * 4;
    for (int r = 0; r < 4; ++r){
        const float4* src = (const float4*)(W1 + (size_t)(h0 + r) * Nn);
        float4* dst = (float4*)rows[r];
        for (int j = tid; j < Nn / 4; j += 256) dst[j] = src[j];
    }
    __syncthreads();
    int t = tid;
    int b0 = boff[t], b1 = boff[t + 1];
    float s0 = 0.f, s1 = 0.f, s2 = 0.f, s3 = 0.f;
    for (int k = b0; k < b1; ++k){
        int i = sidx[k];
        s0 += rows[0][i]; s1 += rows[1][i]; s2 += rows[2][i]; s3 += rows[3][i];
    }
    G_T[(size_t)(h0 + 0) * Tt + t] = s0;
    G_T[(size_t)(h0 + 1) * Tt + t] = s1;
    G_T[(size_t)(h0 + 2) * Tt + t] = s2;
    G_T[(size_t)(h0 + 3) * Tt + t] = s3;
}

// ---------------- k_c1: c1[t][h] = sum_{tau=max(0,t-7)..t} G_T[h][tau] ----------------
__global__ __launch_bounds__(256) void k_c1(const float* __restrict__ G_T,
                                            float* __restrict__ c1){
    __shared__ float tile[32][Tt + 1];
    int tid = threadIdx.x;
    int h0 = blockIdx.x * 32;
    for (int r = 0; r < 32; ++r) tile[r][tid] = G_T[(size_t)(h0 + r) * Tt + tid];
    __syncthreads();
    int hs = tid & 31, ts = tid >> 5;
    for (int tb = 0; tb < 32; ++tb){
        int t = tb * 8 + ts;
        int lo = (t - 7 < 0) ? 0 : t - 7;
        float s = 0.f;
        for (int u = lo; u <= t; ++u) s += tile[hs][u];
        c1[(size_t)t * Hn + h0 + hs] = s;
    }
}

// ---------------- k_sim1 body ----------------
__device__ __forceinline__ void sim1_body(int TT, float4 (&BUF)[8], float (&mem)[32],
        const float4* c4, int tid, int lane, int w,
        float* s_thv, float* s_tsv, float* s_r1p,
        float (*s_pv)[4], int (*s_pi)[4], int* s_j1, int* s_ff){
    const int p_ = TT & 1;
    float bv0 = -3.4e38f, bv1 = -3.4e38f, bv2 = -3.4e38f, bv3 = -3.4e38f;
    int bk0 = 0, bk1 = 1, bk2 = 2, bk3 = 3;
#pragma unroll
    for (int j = 0; j < 8; ++j){
        int kb = j * 4;
        float c0 = BUF[j].x, c1v = BUF[j].y, c2 = BUF[j].z, c3 = BUF[j].w;
        mem[kb+0] = __fadd_rn(__fmul_rn(0.9f, mem[kb+0]), c0);
        mem[kb+1] = __fadd_rn(__fmul_rn(0.9f, mem[kb+1]), c1v);
        mem[kb+2] = __fadd_rn(__fmul_rn(0.9f, mem[kb+2]), c2);
        mem[kb+3] = __fadd_rn(__fmul_rn(0.9f, mem[kb+3]), c3);
        if (mem[kb+0] > bv0){ bv0 = mem[kb+0]; bk0 = kb+0; }
        if (mem[kb+1] > bv1){ bv1 = mem[kb+1]; bk1 = kb+1; }
        if (mem[kb+2] > bv2){ bv2 = mem[kb+2]; bk2 = kb+2; }
        if (mem[kb+3] > bv3){ bv3 = mem[kb+3]; bk3 = kb+3; }
    }
    // prefetch row TT+2 into BUF (stays in flight across raw barriers)
    {
        int tn = TT + 2; if (tn >= Tt) tn = Tt - 1;
        const float4* pn = c4 + (size_t)tn * (Hn/4) + tid * 8;
#pragma unroll
        for (int j = 0; j < 8; ++j) BUF[j] = pn[j];
    }
    float bv = bv0; int bk = bk0;
    if (bv1 > bv || (bv1 == bv && bk1 < bk)){ bv = bv1; bk = bk1; }
    if (bv2 > bv || (bv2 == bv && bk2 < bk)){ bv = bv2; bk = bk2; }
    if (bv3 > bv || (bv3 == bv && bk3 < bk)){ bv = bv3; bk = bk3; }
    int bi = (tid << 5) + bk;
#pragma unroll
    for (int off = 32; off >= 1; off >>= 1){
        float ov = __shfl_down(bv, off);
        int   oi = __shfl_down(bi, off);
        if (ov > bv || (ov == bv && oi < bi)){ bv = ov; bi = oi; }
    }
    if (lane == 0){ s_pv[p_][w] = bv; s_pi[p_][w] = bi; }
    bar_lgkm();
    float fv = s_pv[p_][0]; int fi = s_pi[p_][0];
    { float v = s_pv[p_][1]; int i = s_pi[p_][1]; if (v > fv || (v == fv && i < fi)){ fv = v; fi = i; } }
    { float v = s_pv[p_][2]; int i = s_pi[p_][2]; if (v > fv || (v == fv && i < fi)){ fv = v; fi = i; } }
    { float v = s_pv[p_][3]; int i = s_pi[p_][3]; if (v > fv || (v == fv && i < fi)){ fv = v; fi = i; } }
    int kw = -1;
    if ((fi >> 5) == tid){
        float tf = (float)TT;
        float tsv = s_tsv[fi];
        float cf = tf - 1.0f - tsv;                      // # of decay steps applied
        float thb = __fsub_rn(s_thv[fi], __fmul_rn(0.05f, cf));
        if (cf > 0.5f) thb = fmaxf(thb, 150.f);          // clamp only if >=1 decay
        int fire = (fv > thb) ? 1 : 0;
        if (fire){
            kw = fi & 31;
            if (s_r1p[fi] == 0.f) s_r1p[fi] = tf + 1.0f;
            s_thv[fi] = fminf(fmaxf(__fadd_rn(__fsub_rn(thb, 0.05f), 5.0f), 150.f), 400.f);
            s_tsv[fi] = tf;
        }
        s_j1[TT] = fi; s_ff[TT] = fire;
    }
    if (__any(kw >= 0)){                                  // only owner's wave pays
#pragma unroll
        for (int k = 0; k < 32; ++k) if (k == kw) mem[k] = 0.f;
    }
}

// ---------------- k_sim1: 256 threads, 32 h/thread, 1 raw barrier/step ----------------
__global__ __launch_bounds__(256, 1) void k_sim1(
        const float* __restrict__ c1, const float* __restrict__ thr1,
        float* __restrict__ r1pre, float* __restrict__ o_r1,
        int* __restrict__ j1, int* __restrict__ fired){
    const int tid = threadIdx.x;
    const int lane = tid & 63, w = tid >> 6;

    __shared__ float s_thv[Hn], s_tsv[Hn], s_r1p[Hn];   // 96 KB
    __shared__ float s_pv[2][4];
    __shared__ int   s_pi[2][4];
    __shared__ int   s_j1[Tt], s_ff[Tt];

    for (int i = tid; i < Hn; i += 256){
        s_thv[i] = thr1[i]; s_tsv[i] = -1.0f; s_r1p[i] = 0.0f;
    }

    float mem[32];
#pragma unroll
    for (int k = 0; k < 32; ++k) mem[k] = 0.f;

    const float4* c4 = (const float4*)c1;
    float4 A[8], B[8];
#pragma unroll
    for (int j = 0; j < 8; ++j) A[j] = c4[tid * 8 + j];
#pragma unroll
    for (int j = 0; j < 8; ++j) B[j] = c4[(Hn/4) + tid * 8 + j];

    bar_lgkm();

    for (int t = 0; t < Tt; t += 2){
        sim1_body(t,     A, mem, c4, tid, lane, w, s_thv, s_tsv, s_r1p, s_pv, s_pi, s_j1, s_ff);
        sim1_body(t + 1, B, mem, c4, tid, lane, w, s_thv, s_tsv, s_r1p, s_pv, s_pi, s_j1, s_ff);
    }

    bar_lgkm();
    for (int i = tid; i < Hn; i += 256){
        float rp = s_r1p[i];
        r1pre[i] = rp;
        o_r1[i] = (rp == 0.f) ? 256.f : rp;
    }
    j1[tid] = s_j1[tid]; fired[tid] = s_ff[tid];
}

// ---------------- k_w2gather: W2cols[t][n] = fired[t] ? W2[n][j1[t]] : 0 ----------------
__global__ __launch_bounds__(256) void k_w2gather(const float* __restrict__ W2,
        const int* __restrict__ j1, const int* __restrict__ fired,
        float* __restrict__ W2cols){
    int t = blockIdx.x, tid = threadIdx.x;
    float* dst = W2cols + (size_t)t * Nn;
    if (!fired[t]){
        for (int n = tid; n < Nn; n += 256) dst[n] = 0.f;
    } else {
        int col = j1[t];
        for (int n = tid; n < Nn; n += 256) dst[n] = W2[(size_t)n * Hn + col];
    }
}

// ---------------- k_w3t: W3T[n][c] = W3[c][n] ----------------
__global__ __launch_bounds__(256) void k_w3t(const float* __restrict__ W3,
                                             float* __restrict__ W3T){
    __shared__ float tl[64][65];
    int bx = blockIdx.x & 63, by = blockIdx.x >> 6;
    int n0 = bx * 64, c0 = by * 64;
    int tid = threadIdx.x;
    for (int e = tid; e < 64 * 64; e += 256){
        int r = e >> 6, cc = e & 63;
        tl[r][cc] = W3[(size_t)(c0 + r) * Nn + n0 + cc];
    }
    __syncthreads();
    for (int e = tid; e < 64 * 64; e += 256){
        int rn = e >> 6, cc = e & 63;
        W3T[(size_t)(n0 + rn) * Cn + c0 + cc] = tl[cc][rn];
    }
}

// ---------------- k_sim2 body ----------------
__device__ __forceinline__ void sim2_body(int TT, float4 (&BUF)[4],
        float (&mem2)[16], float (&tv2)[16], float (&r2p)[16],
        float &m3a, float &m3b, float &th3a, float &th3b,
        float &ts3a, float &ts3b, float &r3a, float &r3b, int &z3,
        const float4* wc, const float* W3T, int tid, int lane, int w,
        int (*s_wtot)[4], int* s_list){
    const int p_ = TT & 1;
    int bits = 0;
#pragma unroll
    for (int j = 0; j < 4; ++j){
        float c0 = BUF[j].x, c1v = BUF[j].y, c2 = BUF[j].z, c3 = BUF[j].w;
        float cin[4] = {c0, c1v, c2, c3};
#pragma unroll
        for (int q = 0; q < 4; ++q){
            int k = j * 4 + q;
            float m = __fadd_rn(__fmul_rn(0.8f, mem2[k]), cin[q]);
            if (m > tv2[k]){
                m = __fsub_rn(m, tv2[k]);
                if (r2p[k] == 0.f) r2p[k] = (float)TT + 1.0f;
                bits |= (1 << k);
            }
            mem2[k] = m;
        }
    }
    // prefetch row TT+2
    {
        int tn = TT + 2; if (tn >= Tt) tn = Tt - 1;
        const float4* pn = wc + (size_t)tn * (Nn/4) + tid * 4;
#pragma unroll
        for (int j = 0; j < 4; ++j) BUF[j] = pn[j];
    }
    int cnt = __popc((unsigned)bits);
    int inc = cnt;
#pragma unroll
    for (int off = 1; off < 64; off <<= 1){
        int v = __shfl_up(inc, off);
        if (lane >= off) inc += v;
    }
    if (lane == 63) s_wtot[p_][w] = inc;
    bar_lgkm();
    int t0 = s_wtot[p_][0], t1 = s_wtot[p_][1], t2 = s_wtot[p_][2], t3 = s_wtot[p_][3];
    int CNT = t0 + t1 + t2 + t3;
    int base = ((w > 0) ? t0 : 0) + ((w > 1) ? t1 : 0) + ((w > 2) ? t2 : 0) + inc - cnt;
    if (bits){
#pragma unroll
        for (int k = 0; k < 16; ++k)
            if ((bits >> k) & 1) s_list[base++] = tid * 16 + k;
    }
    bar_lgkm();
    if (w == 0 && (CNT > 0 || !z3)){
        float da = 0.f, db = 0.f;
        for (int e = 0; e < CNT; ++e){
            int n = s_list[e];
            const float* row = W3T + (size_t)n * Cn;
            da = __fadd_rn(da, row[lane]);
            db = __fadd_rn(db, row[lane + 64]);
        }
        m3a = __fadd_rn(__fmul_rn(0.9f, m3a), da);
        m3b = __fadd_rn(__fmul_rn(0.9f, m3b), db);
        float bv; int bi;
        if (m3b > m3a){ bv = m3b; bi = lane + 64; } else { bv = m3a; bi = lane; }
#pragma unroll
        for (int off = 32; off >= 1; off >>= 1){
            float ov = __shfl_down(bv, off);
            int   oi = __shfl_down(bi, off);
            if (ov > bv || (ov == bv && oi < bi)){ bv = ov; bi = oi; }
        }
        bv = __shfl(bv, 0); bi = __shfl(bi, 0);
        int fire = 0;
        if (lane == (bi & 63)){
            float thvv = (bi >= 64) ? th3b : th3a;
            float tss  = (bi >= 64) ? ts3b : ts3a;
            float tf = (float)TT;
            float cf = tf - 1.0f - tss;
            float thb = __fsub_rn(thvv, __fmul_rn(0.05f, cf));
            if (cf > 0.5f) thb = fmaxf(thb, 50.f);
            fire = (bv > thb) ? 1 : 0;
            if (fire){
                float nv = fminf(fmaxf(__fadd_rn(__fsub_rn(thb, 0.05f), 5.0f), 50.f), 200.f);
                if (bi >= 64){ th3b = nv; ts3b = tf; if (r3b == 0.f) r3b = tf + 1.0f; }
                else         { th3a = nv; ts3a = tf; if (r3a == 0.f) r3a = tf + 1.0f; }
            }
        }
        fire = __shfl(fire, (bi & 63));
        if (fire){ m3a = 0.f; m3b = 0.f; z3 = 1; }
        else if (CNT > 0) z3 = 0;
    }
}

// ---------------- k_sim2: 256 threads, 16 n/thread; layer-3 in wave0 regs ----------------
__global__ __launch_bounds__(256, 1) void k_sim2(const float* __restrict__ W2cols,
        const float* __restrict__ W3T, const float* __restrict__ thr2,
        const float* __restrict__ thr3, float* __restrict__ o_r2,
        float* __restrict__ o_r3){
    const int tid = threadIdx.x, lane = tid & 63, w = tid >> 6;
    __shared__ int s_wtot[2][4];
    __shared__ int s_list[Nn];    // 16 KB

    float mem2[16], tv2[16], r2p[16];
    {
        const float4* tq = (const float4*)thr2;
#pragma unroll
        for (int j = 0; j < 4; ++j){
            float4 v = tq[tid * 4 + j];
            tv2[j*4+0] = v.x; tv2[j*4+1] = v.y; tv2[j*4+2] = v.z; tv2[j*4+3] = v.w;
        }
    }
#pragma unroll
    for (int k = 0; k < 16; ++k){ mem2[k] = 0.f; r2p[k] = 0.f; }

    float m3a = 0.f, m3b = 0.f, th3a = 0.f, th3b = 0.f;
    float ts3a = -1.f, ts3b = -1.f, r3a = 0.f, r3b = 0.f;
    int z3 = 1;
    if (w == 0){ th3a = thr3[lane]; th3b = thr3[lane + 64]; }

    const float4* wc = (const float4*)W2cols;
    float4 A[4], B[4];
#pragma unroll
    for (int j = 0; j < 4; ++j) A[j] = wc[tid * 4 + j];
#pragma unroll
    for (int j = 0; j < 4; ++j) B[j] = wc[(Nn/4) + tid * 4 + j];

    for (int t = 0; t < Tt; t += 2){
        sim2_body(t,     A, mem2, tv2, r2p, m3a, m3b, th3a, th3b, ts3a, ts3b, r3a, r3b, z3,
                  wc, W3T, tid, lane, w, s_wtot, s_list);
        sim2_body(t + 1, B, mem2, tv2, r2p, m3a, m3b, th3a, th3b, ts3a, ts3b, r3a, r3b, z3,
                  wc, W3T, tid, lane, w, s_wtot, s_list);
    }

#pragma unroll
    for (int k = 0; k < 16; ++k){
        float rp = r2p[k];
        o_r2[tid * 16 + k] = (rp == 0.f) ? 256.f : rp;
    }
    if (w == 0){
        o_r3[lane]      = (r3a == 0.f) ? 256.f : r3a;
        o_r3[lane + 64] = (r3b == 0.f) ? 256.f : r3b;
    }
}

// ---------------- k_scalars: zeta, rho, error, error_scalar ----------------
__global__ __launch_bounds__(1024) void k_scalars(const float* __restrict__ image,
        const float* __restrict__ r1pre, const float* __restrict__ o_r1,
        const float* __restrict__ o_r2, float* __restrict__ zeta,
        float* __restrict__ rho, float* __restrict__ o_err,
        float* __restrict__ o_es){
    int tid = threadIdx.x;
    for (int h = tid; h < Hn; h += 1024){
        float r1f = o_r1[h];
        float mask = (r1pre[h] != 0.f) ? 1.f : 0.f;
        zeta[h] = __fmul_rn(__fmul_rn(__fsub_rn(256.f, r1f), mask), 0.00390625f);
    }
    float acc = 0.f;
    for (int n = tid; n < Nn; n += 1024){
        float img = __fmul_rn(256.f, image[n]);
        float r2f = o_r2[n];
        float e = __fmul_rn(__fsub_rn(img, __fsub_rn(r2f, 4.0f)), 0.00390625f);
        o_err[n] = e;
        rho[n] = __fadd_rn(__fmul_rn(__fsub_rn(__fsub_rn(r2f, 4.0f), img), 0.00390625f), 0.15f);
        acc = __fadd_rn(acc, __fmul_rn(e, e));
    }
    __shared__ float red[16];
    for (int off = 32; off >= 1; off >>= 1) acc += __shfl_down(acc, off);
    int lane = tid & 63, w = tid >> 6;
    if (lane == 0) red[w] = acc;
    __syncthreads();
    if (tid == 0){
        float s = 0.f;
        for (int q = 0; q < 16; ++q) s += red[q];
        *o_es = s;
    }
}

// ---------------- STDP weight-update kernels (float4-vectorized) ----------------
__global__ __launch_bounds__(256) void k_w1new(const float* __restrict__ W1,
        const float* __restrict__ image, const float* __restrict__ r1pre,
        const float* __restrict__ o_r1, float* __restrict__ o_W1){
    int h = blockIdx.x, tid = threadIdx.x;
    float r1f = o_r1[h];
    bool msk = (r1pre[h] != 0.f);
    const float4* src = (const float4*)(W1 + (size_t)h * Nn);
    float4* dst = (float4*)(o_W1 + (size_t)h * Nn);
    const float4* img4 = (const float4*)image;
#pragma unroll
    for (int i = tid; i < Nn / 4; i += 256){
        float4 s = src[i];
        if (msk){
            float4 im = img4[i];
            s.x = __fadd_rn(s.x, stdp_f(__fsub_rn(r1f, __fmul_rn(256.f, im.x))));
            s.y = __fadd_rn(s.y, stdp_f(__fsub_rn(r1f, __fmul_rn(256.f, im.y))));
            s.z = __fadd_rn(s.z, stdp_f(__fsub_rn(r1f, __fmul_rn(256.f, im.z))));
            s.w = __fadd_rn(s.w, stdp_f(__fsub_rn(r1f, __fmul_rn(256.f, im.w))));
        } else {
            s.x = __fadd_rn(s.x, 0.01f);
            s.y = __fadd_rn(s.y, 0.01f);
            s.z = __fadd_rn(s.z, 0.01f);
            s.w = __fadd_rn(s.w, 0.01f);
        }
        dst[i] = s;
    }
}

__device__ __forceinline__ float clamp01(float v){
    return fminf(fmaxf(v, 0.f), 1.f);
}

__global__ __launch_bounds__(256) void k_w2new(const float* __restrict__ W2,
        const float* __restrict__ o_r1, const float* __restrict__ zeta,
        const float* __restrict__ o_r2, const float* __restrict__ rho,
        float* __restrict__ o_W2){
    int n = blockIdx.x, tid = threadIdx.x;
    float r2f = o_r2[n], rh = rho[n];
    const float4* src = (const float4*)(W2 + (size_t)n * Hn);
    float4* dst = (float4*)(o_W2 + (size_t)n * Hn);
    const float4* r14 = (const float4*)o_r1;
    const float4* zt4 = (const float4*)zeta;
#pragma unroll
    for (int i = tid; i < Hn / 4; i += 256){
        float4 s = src[i]; float4 rv = r14[i]; float4 zv = zt4[i];
        s.x = clamp01(__fadd_rn(s.x, __fmul_rn(stdp_f(__fsub_rn(r2f, rv.x)), __fmul_rn(rh, zv.x))));
        s.y = clamp01(__fadd_rn(s.y, __fmul_rn(stdp_f(__fsub_rn(r2f, rv.y)), __fmul_rn(rh, zv.y))));
        s.z = clamp01(__fadd_rn(s.z, __fmul_rn(stdp_f(__fsub_rn(r2f, rv.z)), __fmul_rn(rh, zv.z))));
        s.w = clamp01(__fadd_rn(s.w, __fmul_rn(stdp_f(__fsub_rn(r2f, rv.w)), __fmul_rn(rh, zv.w))));
        dst[i] = s;
    }
}

__global__ __launch_bounds__(256) void k_w3new(const float* __restrict__ W3,
        const float* __restrict__ o_r2, const float* __restrict__ o_r3,
        float* __restrict__ o_W3){
    int c = blockIdx.x, tid = threadIdx.x;
    float r3f = o_r3[c];
    const float4* src = (const float4*)(W3 + (size_t)c * Nn);
    float4* dst = (float4*)(o_W3 + (size_t)c * Nn);
    const float4* r24 = (const float4*)o_r2;
#pragma unroll
    for (int i = tid; i < Nn / 4; i += 256){
        float4 s = src[i]; float4 rv = r24[i];
        s.x = __fadd_rn(s.x, stdp_f(__fsub_rn(r3f, rv.x)));
        s.y = __fadd_rn(s.y, stdp_f(__fsub_rn(r3f, rv.y)));
        s.z = __fadd_rn(s.z, stdp_f(__fsub_rn(r3f, rv.z)));
        s.w = __fadd_rn(s.w, stdp_f(__fsub_rn(r3f, rv.w)));
        dst[i] = s;
    }
}

extern "C" void kernel_launch(void* const* d_in, const int* in_sizes, int n_in,
                              void* d_out, int out_size, void* d_ws, size_t ws_size,
                              hipStream_t stream){
    const float* image = (const float*)d_in[0];
    const float* W1   = (const float*)d_in[1];
    const float* W2   = (const float*)d_in[2];
    const float* W3   = (const float*)d_in[3];
    const float* thr1 = (const float*)d_in[4];
    const float* thr2 = (const float*)d_in[5];
    const float* thr3 = (const float*)d_in[6];

    float* out  = (float*)d_out;
    float* o_err = out;                       // [4096]
    float* o_es  = out + 4096;                // [1]
    float* o_r1  = out + 4097;                // [8192]
    float* o_r2  = out + 12289;               // [4096]
    float* o_r3  = out + 16385;               // [128]
    float* o_W1  = out + 16513;               // [8192*4096]
    float* o_W2  = o_W1 + (size_t)Hn * Nn;    // [4096*8192]
    float* o_W3  = o_W2 + (size_t)Nn * Hn;    // [128*4096]

    float* ws = (float*)d_ws;
    float* G_T    = ws;                            // H*T
    float* c1     = G_T + (size_t)Hn * Tt;         // T*H
    float* W2cols = c1 + (size_t)Tt * Hn;          // T*N
    float* W3T    = W2cols + (size_t)Tt * Nn;      // N*C
    float* r1pre  = W3T + (size_t)Nn * Cn;         // H
    float* zeta   = r1pre + Hn;                    // H
    float* rho    = zeta + Hn;                     // N
    int* start = (int*)(rho + Nn);                 // N
    int* boff  = start + Nn;                       // T+1
    int* sidx  = boff + (Tt + 1);                  // N
    int* j1    = sidx + Nn;                        // T
    int* fired = j1 + Tt;                          // T

    k_prep<<<1, 256, 0, stream>>>(image, start, boff, sidx);
    k_gbuckets<<<Hn / 4, 256, 0, stream>>>(W1, boff, sidx, G_T);
    k_c1<<<Hn / 32, 256, 0, stream>>>(G_T, c1);
    k_sim1<<<1, 256, 0, stream>>>(c1, thr1, r1pre, o_r1, j1, fired);
    k_w2gather<<<Tt, 256, 0, stream>>>(W2, j1, fired, W2cols);
    k_w3t<<<128, 256, 0, stream>>>(W3, W3T);
    k_sim2<<<1, 256, 0, stream>>>(W2cols, W3T, thr2, thr3, o_r2, o_r3);
    k_scalars<<<1, 1024, 0, stream>>>(image, r1pre, o_r1, o_r2, zeta, rho, o_err, o_es);
    k_w1new<<<Hn, 256, 0, stream>>>(W1, image, r1pre, o_r1, o_W1);
    k_w2new<<<Nn, 256, 0, stream>>>(W2, o_r1, zeta, o_r2, rho, o_W2);
    k_w3new<<<Cn, 256, 0, stream>>>(W3, o_r2, o_r3, o_W3);
}

// Round 3
// 1005.383 us; speedup vs baseline: 1.3886x; 1.0678x over previous
//
#include <hip/hip_runtime.h>
#include <cstdint>
#include <cstddef>

#define Hn 8192
#define Nn 4096
#define Cn 128
#define Tt 256
#define PWw 8

// stdp(dt) = dt>=0 ? 0.01*exp(-dt/20) : -0.01*exp(dt/20)
__device__ __forceinline__ float stdp_f(float dt){
    const float K = 0.07213475204444817f; // log2(e)/20
    float a = fabsf(dt);
    float e = exp2f(-a * K);
    return dt >= 0.f ? 0.01f * e : -0.01f * e;
}

// raw barrier: publish LDS writes, do NOT drain vmcnt (keeps prefetch in flight)
__device__ __forceinline__ void bar_lgkm(){
    asm volatile("s_waitcnt lgkmcnt(0)" ::: "memory");
    __builtin_amdgcn_s_barrier();
    __builtin_amdgcn_sched_barrier(0);
}

// argmax key packing: value must be >= 0; larger value wins, ties -> smaller index
__device__ __forceinline__ unsigned long long mkkey(float v, int h){
    if (!(v >= 0.f)) return 0ull;
    return ((unsigned long long)__float_as_uint(v) << 32) | (unsigned)(8192 - h);
}
__device__ __forceinline__ int keyh(unsigned long long k){ return 8192 - (int)(k & 0x3FFFu); }
__device__ __forceinline__ float keyv(unsigned long long k){ return __uint_as_float((unsigned)(k >> 32)); }

// block-wide max of u64 keys over 256 threads; all threads get result. one barrier.
__device__ __forceinline__ unsigned long long blkmax256(unsigned long long k, int lane, int w,
        unsigned long long* s4){
#pragma unroll
    for (int off = 32; off >= 1; off >>= 1){
        unsigned long long o = __shfl_down(k, off);
        if (o > k) k = o;
    }
    if (lane == 0) s4[w] = k;
    bar_lgkm();
    unsigned long long a = s4[0], b = s4[1], c = s4[2], d = s4[3];
    unsigned long long m1 = a > b ? a : b;
    unsigned long long m2 = c > d ? c : d;
    return m1 > m2 ? m1 : m2;
}

// th after nup clip-updates from base b: clip into [lo,hi] each step of -0.05
__device__ __forceinline__ float th_lazy2(float b, float lo, float hi, int nup){
    if (nup <= 0) return b;
    float a = fminf(fmaxf(__fsub_rn(b, 0.05f), lo), hi);
    if (nup == 1) return a;
    return fmaxf(__fsub_rn(a, __fmul_rn(0.05f, (float)(nup - 1))), lo);
}

// ---------------- k_prep: start times + deterministic counting sort ----------------
__global__ __launch_bounds__(256) void k_prep(const float* __restrict__ image,
        int* __restrict__ start, int* __restrict__ boff, int* __restrict__ sidx){
    __shared__ int s_start[Nn];
    __shared__ int s_cnt[Tt];
    __shared__ int s_off[Tt + 1];
    int tid = threadIdx.x;
    for (int i = tid; i < Nn; i += 256){
        int s = (int)floorf(__fmul_rn(256.f, image[i]));
        s_start[i] = s; start[i] = s;
    }
    if (tid < Tt) s_cnt[tid] = 0;
    __syncthreads();
    for (int i = tid; i < Nn; i += 256) atomicAdd(&s_cnt[s_start[i]], 1);
    __syncthreads();
    if (tid == 0){
        int acc = 0;
        for (int t = 0; t < Tt; ++t){ s_off[t] = acc; acc += s_cnt[t]; }
        s_off[Tt] = acc;
    }
    __syncthreads();
    {
        int p = s_off[tid];
        for (int i = 0; i < Nn; ++i)
            if (s_start[i] == tid) sidx[p++] = i;
        boff[tid] = s_off[tid];
        if (tid == 0) boff[Tt] = s_off[Tt];
    }
}

// ---------------- k_gbuckets: G_T[h][t] = sum_{i in bucket t} W1[h][i] ----------------
__global__ __launch_bounds__(256) void k_gbuckets(const float* __restrict__ W1,
        const int* __restrict__ boff, const int* __restrict__ sidx,
        float* __restrict__ G_T){
    __shared__ float rows[4][Nn]; // 64 KB
    int tid = threadIdx.x;
    int h0 = blockIdx.x * 4;
    for (int r = 0; r < 4; ++r){
        const float4* src = (const float4*)(W1 + (size_t)(h0 + r) * Nn);
        float4* dst = (float4*)rows[r];
        for (int j = tid; j < Nn / 4; j += 256) dst[j] = src[j];
    }
    __syncthreads();
    int t = tid;
    int b0 = boff[t], b1 = boff[t + 1];
    float s0 = 0.f, s1 = 0.f, s2 = 0.f, s3 = 0.f;
    for (int k = b0; k < b1; ++k){
        int i = sidx[k];
        s0 += rows[0][i]; s1 += rows[1][i]; s2 += rows[2][i]; s3 += rows[3][i];
    }
    G_T[(size_t)(h0 + 0) * Tt + t] = s0;
    G_T[(size_t)(h0 + 1) * Tt + t] = s1;
    G_T[(size_t)(h0 + 2) * Tt + t] = s2;
    G_T[(size_t)(h0 + 3) * Tt + t] = s3;
}

// ---------------- k_c1: c1[t][h] = sum_{tau=max(0,t-7)..t} G_T[h][tau] ----------------
__global__ __launch_bounds__(256) void k_c1(const float* __restrict__ G_T,
                                            float* __restrict__ c1){
    __shared__ float tile[32][Tt + 1];
    int tid = threadIdx.x;
    int h0 = blockIdx.x * 32;
    for (int r = 0; r < 32; ++r) tile[r][tid] = G_T[(size_t)(h0 + r) * Tt + tid];
    __syncthreads();
    int hs = tid & 31, ts = tid >> 5;
    for (int tb = 0; tb < 32; ++tb){
        int t = tb * 8 + ts;
        int lo = (t - 7 < 0) ? 0 : t - 7;
        float s = 0.f;
        for (int u = lo; u <= t; ++u) s += tile[hs][u];
        c1[(size_t)t * Hn + h0 + hs] = s;
    }
}

// ---------------- k_scanM: M[t][h] = no-reset membrane trajectory ----------------
__global__ __launch_bounds__(64) void k_scanM(const float* __restrict__ c1,
        float* __restrict__ M){
    int h = blockIdx.x * 64 + threadIdx.x;
    float m = 0.f;
    for (int t = 0; t < Tt; ++t){
        m = __fadd_rn(__fmul_rn(0.9f, m), c1[(size_t)t * Hn + h]);
        M[(size_t)t * Hn + h] = m;
    }
}

// ---------------- k_tr: transpose [Tt][Hn] -> [Hn][Tt], 64x64 tiles ----------------
__global__ __launch_bounds__(256) void k_tr(const float* __restrict__ src,
        float* __restrict__ dst){
    __shared__ float tl[64][65];
    int bt = blockIdx.x & 3;          // t-tile (4)
    int bh = blockIdx.x >> 2;         // h-tile (128)
    int t0 = bt * 64, h0 = bh * 64;
    int tid = threadIdx.x;
    for (int e = tid; e < 4096; e += 256){
        int r = e >> 6, c = e & 63;
        tl[r][c] = src[(size_t)(t0 + r) * Hn + h0 + c];
    }
    __syncthreads();
    for (int e = tid; e < 4096; e += 256){
        int r = e >> 6, c = e & 63;
        dst[(size_t)(h0 + r) * Tt + t0 + c] = tl[c][r];
    }
}

// ---------------- k_top64: exact per-step top-64 of M (value desc, index asc) ----------------
__global__ __launch_bounds__(256) void k_top64(const float* __restrict__ M,
        float* __restrict__ top_v, int* __restrict__ top_i){
    int t = blockIdx.x, tid = threadIdx.x, lane = tid & 63, w = tid >> 6;
    __shared__ float s_row[Hn];                 // 32 KB
    __shared__ unsigned long long s_red[2][4];
    const float4* src = (const float4*)(M + (size_t)t * Hn);
    float4* d4 = (float4*)s_row;
    for (int j = tid; j < Hn / 4; j += 256) d4[j] = src[j];
    __syncthreads();
    unsigned tk = 0;
    unsigned long long lk = 0ull;
#pragma unroll
    for (int k = 0; k < 32; ++k){
        int i = tid + (k << 8);
        unsigned long long kk = mkkey(s_row[i], i);
        if (kk > lk) lk = kk;
    }
    for (int r = 0; r < 64; ++r){
        unsigned long long wk = blkmax256(lk, lane, w, s_red[r & 1]);
        if (tid == r){
            top_v[t * 64 + r] = keyv(wk);
            top_i[t * 64 + r] = keyh(wk);
        }
        int wh = keyh(wk);
        if ((wh & 255) == tid){
            tk |= (1u << (wh >> 8));
            lk = 0ull;
#pragma unroll
            for (int k = 0; k < 32; ++k){
                if ((tk >> k) & 1u) continue;
                int i = tid + (k << 8);
                unsigned long long kk = mkkey(s_row[i], i);
                if (kk > lk) lk = kk;
            }
        }
    }
}

// ---------------- k_wta1: serial layer-1 WTA over candidates only ----------------
__global__ __launch_bounds__(256, 1) void k_wta1(
        const float* __restrict__ M, const float* __restrict__ c1T,
        const float* __restrict__ top_v, const int* __restrict__ top_i,
        const float* __restrict__ thr1,
        float* __restrict__ r1pre, float* __restrict__ o_r1,
        int* __restrict__ j1, int* __restrict__ fired){
    const int tid = threadIdx.x, lane = tid & 63, w = tid >> 6;
    __shared__ float s_th0[Hn];                 // 32 KB thr1 cache
    __shared__ unsigned s_bit[Hn / 32];         // 1 KB membership bitmap
    __shared__ unsigned short s_slot[Hn];       // 16 KB slot map
    __shared__ int   s_ridx[Tt];
    __shared__ float s_rmem[Tt], s_rth[Tt], s_rr1[Tt];
    __shared__ int   s_rts[Tt];
    __shared__ unsigned long long s_red[4][4];
    __shared__ unsigned long long s_kp[2];
    __shared__ int s_n;
    __shared__ int s_j1[Tt], s_ff[Tt];

    for (int i = tid; i < Hn; i += 256) s_th0[i] = thr1[i];
    for (int i = tid; i < Hn / 32; i += 256) s_bit[i] = 0u;
    if (tid == 0) s_n = 0;
    bar_lgkm();

    // prefetch for t=0
    float tv_n = -1.f; int ti_n = 0;
    if (tid < 64){ tv_n = top_v[tid]; ti_n = top_i[tid]; }
    float cv_n = 0.f;   // R empty at t=0

    for (int t = 0; t < Tt; ++t){
        const int par = t & 1;
        const float tv = tv_n; const int ti = ti_n; const float cv = cv_n;
        const int nR = s_n;
        unsigned long long key = 0ull;
        float mymem = 0.f;
        if (tid < nR){
            mymem = __fadd_rn(__fmul_rn(0.9f, s_rmem[tid]), cv);
            s_rmem[tid] = mymem;
            key = mkkey(mymem, s_ridx[tid]);
        }
        if (tid < 64){
            if (!((s_bit[ti >> 5] >> (ti & 31)) & 1u)){
                unsigned long long k2 = mkkey(tv, ti);
                if (k2 > key) key = k2;
            }
            if (tid == 63) s_kp[par] = mkkey(tv, ti);
        }
        unsigned long long wk = blkmax256(key, lane, w, s_red[par]);
        if (wk < s_kp[par]){
            // rare exact fallback: full row scan over non-members + R part
            unsigned long long fk = 0ull;
            if (tid < nR) fk = mkkey(mymem, s_ridx[tid]);
            const float* Mrow = M + (size_t)t * Hn;
#pragma unroll 4
            for (int k = 0; k < 32; ++k){
                int i = tid + (k << 8);
                float x = Mrow[i];
                if (!((s_bit[i >> 5] >> (i & 31)) & 1u)){
                    unsigned long long kk = mkkey(x, i);
                    if (kk > fk) fk = kk;
                }
            }
            wk = blkmax256(fk, lane, w, s_red[2 + par]);
        }
        const int wh = keyh(wk);
        const float wv = keyv(wk);
        if (tid == 0){
            int inr = (s_bit[wh >> 5] >> (wh & 31)) & 1u;
            int slot = inr ? (int)s_slot[wh] : -1;
            float th_eff;
            if (slot >= 0) th_eff = th_lazy2(s_rth[slot], 150.f, 400.f, t - s_rts[slot] - 1);
            else           th_eff = th_lazy2(s_th0[wh], 150.f, 400.f, t);
            int fire = (wv > th_eff) ? 1 : 0;
            s_j1[t] = wh; s_ff[t] = fire;
            if (fire){
                if (slot < 0){
                    slot = nR;
                    s_ridx[slot] = wh;
                    s_slot[wh] = (unsigned short)slot;
                    s_bit[wh >> 5] |= (1u << (wh & 31));
                    s_rr1[slot] = (float)(t + 1);
                    s_n = nR + 1;
                }
                s_rmem[slot] = 0.f;                 // reset-to-zero
                s_rth[slot] = fminf(fmaxf(__fadd_rn(__fsub_rn(th_eff, 0.05f), 5.0f), 150.f), 400.f);
                s_rts[slot] = t;
            }
        }
        bar_lgkm();
        // prefetch next step's member drives + top list
        const int nR2 = s_n;
        int t2 = (t + 1 < Tt) ? t + 1 : Tt - 1;
        cv_n = (tid < nR2) ? c1T[(size_t)s_ridx[tid] * Tt + t2] : 0.f;
        if (tid < 64){ tv_n = top_v[t2 * 64 + tid]; ti_n = top_i[t2 * 64 + tid]; }
    }
    bar_lgkm();
    for (int i = tid; i < Hn; i += 256){
        float v = 0.f;
        if ((s_bit[i >> 5] >> (i & 31)) & 1u) v = s_rr1[s_slot[i]];
        r1pre[i] = v;
        o_r1[i] = (v == 0.f) ? 256.f : v;
    }
    j1[tid] = s_j1[tid];
    fired[tid] = s_ff[tid];
}

// ---------------- k_w2gather: W2cols[t][n] = fired[t] ? W2[n][j1[t]] : 0 ----------------
__global__ __launch_bounds__(256) void k_w2gather(const float* __restrict__ W2,
        const int* __restrict__ j1, const int* __restrict__ fired,
        float* __restrict__ W2cols){
    int t = blockIdx.x, tid = threadIdx.x;
    float* dst = W2cols + (size_t)t * Nn;
    if (!fired[t]){
        for (int n = tid; n < Nn; n += 256) dst[n] = 0.f;
    } else {
        int col = j1[t];
        for (int n = tid; n < Nn; n += 256) dst[n] = W2[(size_t)n * Hn + col];
    }
}

// ---------------- k_zero: zero spike bitmasks ----------------
__global__ __launch_bounds__(256) void k_zero(unsigned* __restrict__ p, int n){
    int i = blockIdx.x * 256 + threadIdx.x;
    if (i < n) p[i] = 0u;
}

// ---------------- k_lif2: layer 2, per-neuron independent (no WTA) ----------------
__global__ __launch_bounds__(64) void k_lif2(const float* __restrict__ W2cols,
        const float* __restrict__ thr2, float* __restrict__ o_r2,
        unsigned* __restrict__ spkb, unsigned* __restrict__ anyv){
    int n = blockIdx.x * 64 + threadIdx.x;
    float tv = thr2[n];
    float m = 0.f, rp = 0.f;
    for (int t = 0; t < Tt; ++t){
        float u = W2cols[(size_t)t * Nn + n];
        m = __fadd_rn(__fmul_rn(0.8f, m), u);
        if (m > tv){
            m = __fsub_rn(m, tv);                 // reset-by-subtract
            if (rp == 0.f) rp = (float)(t + 1);
            atomicOr(&spkb[t * (Nn / 32) + (n >> 5)], 1u << (n & 31));
            atomicOr(&anyv[t], 1u);
        }
    }
    o_r2[n] = (rp == 0.f) ? 256.f : rp;
}

// ---------------- k_w3t: W3T[n][c] = W3[c][n] ----------------
__global__ __launch_bounds__(256) void k_w3t(const float* __restrict__ W3,
                                             float* __restrict__ W3T){
    __shared__ float tl[64][65];
    int bx = blockIdx.x & 63, by = blockIdx.x >> 6;
    int n0 = bx * 64, c0 = by * 64;
    int tid = threadIdx.x;
    for (int e = tid; e < 64 * 64; e += 256){
        int r = e >> 6, cc = e & 63;
        tl[r][cc] = W3[(size_t)(c0 + r) * Nn + n0 + cc];
    }
    __syncthreads();
    for (int e = tid; e < 64 * 64; e += 256){
        int rn = e >> 6, cc = e & 63;
        W3T[(size_t)(n0 + rn) * Cn + c0 + cc] = tl[cc][rn];
    }
}

// ---------------- k_sim3: layer 3 WTA; skips exact-zero quiet steps ----------------
__global__ __launch_bounds__(128, 1) void k_sim3(const unsigned* __restrict__ spkb,
        const unsigned* __restrict__ anyv, const float* __restrict__ W3T,
        const float* __restrict__ thr3, float* __restrict__ o_r3){
    int tid = threadIdx.x, lane = tid & 63, w = tid >> 6;
    __shared__ unsigned s_any[Tt];
    __shared__ unsigned long long s_r2[2];
    __shared__ int s_fire;
    for (int i = tid; i < Tt; i += 128) s_any[i] = anyv[i];
    float m = 0.f, th0 = thr3[tid], rp = 0.f, thv = 0.f;
    int ts = -1;
    int zero = 1;
    __syncthreads();
    for (int t = 0; t < Tt; ++t){
        if (zero && s_any[t] == 0u) continue;     // mem3 == 0 exactly, no drive: no-op step
        float d = 0.f;
        if (s_any[t]){
            for (int ww = 0; ww < Nn / 32; ++ww){
                unsigned bits = spkb[t * (Nn / 32) + ww];
                while (bits){
                    int b = __ffs(bits) - 1;
                    bits &= bits - 1;
                    d = __fadd_rn(d, W3T[(size_t)(ww * 32 + b) * Cn + tid]);
                }
            }
        }
        m = __fadd_rn(__fmul_rn(0.9f, m), d);
        unsigned long long k = mkkey(m, tid);
#pragma unroll
        for (int off = 32; off >= 1; off >>= 1){
            unsigned long long o = __shfl_down(k, off);
            if (o > k) k = o;
        }
        if (lane == 0) s_r2[w] = k;
        __syncthreads();
        unsigned long long wk = s_r2[0] > s_r2[1] ? s_r2[0] : s_r2[1];
        int wc = keyh(wk);
        float wv = keyv(wk);
        if (tid == wc){
            float te = (ts < 0) ? th_lazy2(th0, 50.f, 200.f, t)
                                : th_lazy2(thv, 50.f, 200.f, t - ts - 1);
            int f = (wv > te) ? 1 : 0;
            s_fire = f;
            if (f){
                thv = fminf(fmaxf(__fadd_rn(__fsub_rn(te, 0.05f), 5.0f), 50.f), 200.f);
                ts = t;
                if (rp == 0.f) rp = (float)(t + 1);
            }
        }
        __syncthreads();
        if (s_fire){ m = 0.f; zero = 1; }
        else zero = 0;
        __syncthreads();
    }
    o_r3[tid] = (rp == 0.f) ? 256.f : rp;
}

// ---------------- k_scalars: zeta, rho, error, error_scalar ----------------
__global__ __launch_bounds__(1024) void k_scalars(const float* __restrict__ image,
        const float* __restrict__ r1pre, const float* __restrict__ o_r1,
        const float* __restrict__ o_r2, float* __restrict__ zeta,
        float* __restrict__ rho, float* __restrict__ o_err,
        float* __restrict__ o_es){
    int tid = threadIdx.x;
    for (int h = tid; h < Hn; h += 1024){
        float r1f = o_r1[h];
        float mask = (r1pre[h] != 0.f) ? 1.f : 0.f;
        zeta[h] = __fmul_rn(__fmul_rn(__fsub_rn(256.f, r1f), mask), 0.00390625f);
    }
    float acc = 0.f;
    for (int n = tid; n < Nn; n += 1024){
        float img = __fmul_rn(256.f, image[n]);
        float r2f = o_r2[n];
        float e = __fmul_rn(__fsub_rn(img, __fsub_rn(r2f, 4.0f)), 0.00390625f);
        o_err[n] = e;
        rho[n] = __fadd_rn(__fmul_rn(__fsub_rn(__fsub_rn(r2f, 4.0f), img), 0.00390625f), 0.15f);
        acc = __fadd_rn(acc, __fmul_rn(e, e));
    }
    __shared__ float red[16];
    for (int off = 32; off >= 1; off >>= 1) acc += __shfl_down(acc, off);
    int lane = tid & 63, w = tid >> 6;
    if (lane == 0) red[w] = acc;
    __syncthreads();
    if (tid == 0){
        float s = 0.f;
        for (int q = 0; q < 16; ++q) s += red[q];
        *o_es = s;
    }
}

// ---------------- STDP weight-update kernels (float4-vectorized) ----------------
__global__ __launch_bounds__(256) void k_w1new(const float* __restrict__ W1,
        const float* __restrict__ image, const float* __restrict__ r1pre,
        const float* __restrict__ o_r1, float* __restrict__ o_W1){
    int h = blockIdx.x, tid = threadIdx.x;
    float r1f = o_r1[h];
    bool msk = (r1pre[h] != 0.f);
    const float4* src = (const float4*)(W1 + (size_t)h * Nn);
    float4* dst = (float4*)(o_W1 + (size_t)h * Nn);
    const float4* img4 = (const float4*)image;
#pragma unroll
    for (int i = tid; i < Nn / 4; i += 256){
        float4 s = src[i];
        if (msk){
            float4 im = img4[i];
            s.x = __fadd_rn(s.x, stdp_f(__fsub_rn(r1f, __fmul_rn(256.f, im.x))));
            s.y = __fadd_rn(s.y, stdp_f(__fsub_rn(r1f, __fmul_rn(256.f, im.y))));
            s.z = __fadd_rn(s.z, stdp_f(__fsub_rn(r1f, __fmul_rn(256.f, im.z))));
            s.w = __fadd_rn(s.w, stdp_f(__fsub_rn(r1f, __fmul_rn(256.f, im.w))));
        } else {
            s.x = __fadd_rn(s.x, 0.01f);
            s.y = __fadd_rn(s.y, 0.01f);
            s.z = __fadd_rn(s.z, 0.01f);
            s.w = __fadd_rn(s.w, 0.01f);
        }
        dst[i] = s;
    }
}

__device__ __forceinline__ float clamp01(float v){
    return fminf(fmaxf(v, 0.f), 1.f);
}

__global__ __launch_bounds__(256) void k_w2new(const float* __restrict__ W2,
        const float* __restrict__ o_r1, const float* __restrict__ zeta,
        const float* __restrict__ o_r2, const float* __restrict__ rho,
        float* __restrict__ o_W2){
    int n = blockIdx.x, tid = threadIdx.x;
    float r2f = o_r2[n], rh = rho[n];
    const float4* src = (const float4*)(W2 + (size_t)n * Hn);
    float4* dst = (float4*)(o_W2 + (size_t)n * Hn);
    const float4* r14 = (const float4*)o_r1;
    const float4* zt4 = (const float4*)zeta;
#pragma unroll
    for (int i = tid; i < Hn / 4; i += 256){
        float4 s = src[i]; float4 rv = r14[i]; float4 zv = zt4[i];
        s.x = clamp01(__fadd_rn(s.x, __fmul_rn(stdp_f(__fsub_rn(r2f, rv.x)), __fmul_rn(rh, zv.x))));
        s.y = clamp01(__fadd_rn(s.y, __fmul_rn(stdp_f(__fsub_rn(r2f, rv.y)), __fmul_rn(rh, zv.y))));
        s.z = clamp01(__fadd_rn(s.z, __fmul_rn(stdp_f(__fsub_rn(r2f, rv.z)), __fmul_rn(rh, zv.z))));
        s.w = clamp01(__fadd_rn(s.w, __fmul_rn(stdp_f(__fsub_rn(r2f, rv.w)), __fmul_rn(rh, zv.w))));
        dst[i] = s;
    }
}

__global__ __launch_bounds__(256) void k_w3new(const float* __restrict__ W3,
        const float* __restrict__ o_r2, const float* __restrict__ o_r3,
        float* __restrict__ o_W3){
    int c = blockIdx.x, tid = threadIdx.x;
    float r3f = o_r3[c];
    const float4* src = (const float4*)(W3 + (size_t)c * Nn);
    float4* dst = (float4*)(o_W3 + (size_t)c * Nn);
    const float4* r24 = (const float4*)o_r2;
#pragma unroll
    for (int i = tid; i < Nn / 4; i += 256){
        float4 s = src[i]; float4 rv = r24[i];
        s.x = __fadd_rn(s.x, stdp_f(__fsub_rn(r3f, rv.x)));
        s.y = __fadd_rn(s.y, stdp_f(__fsub_rn(r3f, rv.y)));
        s.z = __fadd_rn(s.z, stdp_f(__fsub_rn(r3f, rv.z)));
        s.w = __fadd_rn(s.w, stdp_f(__fsub_rn(r3f, rv.w)));
        dst[i] = s;
    }
}

extern "C" void kernel_launch(void* const* d_in, const int* in_sizes, int n_in,
                              void* d_out, int out_size, void* d_ws, size_t ws_size,
                              hipStream_t stream){
    const float* image = (const float*)d_in[0];
    const float* W1   = (const float*)d_in[1];
    const float* W2   = (const float*)d_in[2];
    const float* W3   = (const float*)d_in[3];
    const float* thr1 = (const float*)d_in[4];
    const float* thr2 = (const float*)d_in[5];
    const float* thr3 = (const float*)d_in[6];

    float* out  = (float*)d_out;
    float* o_err = out;                       // [4096]
    float* o_es  = out + 4096;                // [1]
    float* o_r1  = out + 4097;                // [8192]
    float* o_r2  = out + 12289;               // [4096]
    float* o_r3  = out + 16385;               // [128]
    float* o_W1  = out + 16513;               // [8192*4096]
    float* o_W2  = o_W1 + (size_t)Hn * Nn;    // [4096*8192]
    float* o_W3  = o_W2 + (size_t)Nn * Hn;    // [128*4096]

    float* ws = (float*)d_ws;
    float* G_T    = ws;                                  // H*T
    float* c1     = G_T + (size_t)Hn * Tt;               // T*H
    float* c1T    = c1 + (size_t)Tt * Hn;                // H*T
    float* M      = c1T + (size_t)Hn * Tt;               // T*H
    float* W2cols = M + (size_t)Tt * Hn;                 // T*N
    float* W3T    = W2cols + (size_t)Tt * Nn;            // N*C
    float* top_v  = W3T + (size_t)Nn * Cn;               // T*64
    float* r1pre  = top_v + (size_t)Tt * 64;             // H
    float* zeta   = r1pre + Hn;                          // H
    float* rho    = zeta + Hn;                           // N
    int* start  = (int*)(rho + Nn);                      // N
    int* boff   = start + Nn;                            // T+1
    int* sidx   = boff + (Tt + 1);                       // N
    int* j1     = sidx + Nn;                             // T
    int* fired  = j1 + Tt;                               // T
    int* top_i  = fired + Tt;                            // T*64
    unsigned* spkb = (unsigned*)(top_i + Tt * 64);       // T*(N/32)
    unsigned* anyv = spkb + Tt * (Nn / 32);              // T

    const int nzero = Tt * (Nn / 32) + Tt;

    k_prep<<<1, 256, 0, stream>>>(image, start, boff, sidx);
    k_zero<<<(nzero + 255) / 256, 256, 0, stream>>>(spkb, nzero);
    k_gbuckets<<<Hn / 4, 256, 0, stream>>>(W1, boff, sidx, G_T);
    k_c1<<<Hn / 32, 256, 0, stream>>>(G_T, c1);
    k_scanM<<<Hn / 64, 64, 0, stream>>>(c1, M);
    k_tr<<<(Hn / 64) * (Tt / 64), 256, 0, stream>>>(c1, c1T);
    k_top64<<<Tt, 256, 0, stream>>>(M, top_v, top_i);
    k_wta1<<<1, 256, 0, stream>>>(M, c1T, top_v, top_i, thr1, r1pre, o_r1, j1, fired);
    k_w2gather<<<Tt, 256, 0, stream>>>(W2, j1, fired, W2cols);
    k_lif2<<<Nn / 64, 64, 0, stream>>>(W2cols, thr2, o_r2, spkb, anyv);
    k_w3t<<<128, 256, 0, stream>>>(W3, W3T);
    k_sim3<<<1, 128, 0, stream>>>(spkb, anyv, W3T, thr3, o_r3);
    k_scalars<<<1, 1024, 0, stream>>>(image, r1pre, o_r1, o_r2, zeta, rho, o_err, o_es);
    k_w1new<<<Hn, 256, 0, stream>>>(W1, image, r1pre, o_r1, o_W1);
    k_w2new<<<Nn, 256, 0, stream>>>(W2, o_r1, zeta, o_r2, rho, o_W2);
    k_w3new<<<Cn, 256, 0, stream>>>(W3, o_r2, o_r3, o_W3);
}

// Round 4
// 882.940 us; speedup vs baseline: 1.5812x; 1.1387x over previous
//
#include <hip/hip_runtime.h>
#include <cstdint>
#include <cstddef>

#define Hn 8192
#define Nn 4096
#define Cn 128
#define Tt 256
#define CAP 192

typedef unsigned long long ull;

__device__ __forceinline__ ull KEY(float v, int h){
    return ((ull)__float_as_uint(v) << 32) | (unsigned)(8191 - h);
}
__device__ __forceinline__ int KIDX(ull k){ return 8191 - (int)(k & 0xFFFFu); }
__device__ __forceinline__ float KVAL(ull k){ return __uint_as_float((unsigned)(k >> 32)); }

__device__ __forceinline__ ull shflxor64(ull x, int m){
    unsigned lo = (unsigned)x, hi = (unsigned)(x >> 32);
    lo = __shfl_xor(lo, m); hi = __shfl_xor(hi, m);
    return ((ull)hi << 32) | lo;
}

// th after nup clip-updates (decay -0.05 each) from base b, clamped [lo,hi]
__device__ __forceinline__ float th_lazy2(float b, float lo, float hi, int nup){
    if (nup <= 0) return b;
    float a = fminf(fmaxf(__fsub_rn(b, 0.05f), lo), hi);
    if (nup == 1) return a;
    return fmaxf(__fsub_rn(a, __fmul_rn(0.05f, (float)(nup - 1))), lo);
}

__device__ __forceinline__ float clamp01(float v){
    return fminf(fmaxf(v, 0.f), 1.f);
}

// ---------------- k_prep: start buckets + deterministic counting sort (1024 thr) ----------------
__global__ __launch_bounds__(1024) void k_prep(const float* __restrict__ image,
        int* __restrict__ boff, int* __restrict__ sidx, unsigned* __restrict__ anyv){
    __shared__ int s_start[Nn];
    __shared__ int s_c4[4][Tt];
    __shared__ int s_boff[Tt + 1];
    int tid = threadIdx.x;
    for (int i = tid; i < Nn; i += 1024)
        s_start[i] = (int)floorf(__fmul_rn(256.f, image[i]));
    if (tid < Tt) anyv[tid] = 0u;
    __syncthreads();
    int b = tid & 255, q = tid >> 8;
    {
        int c = 0;
        for (int k = 0; k < 1024; ++k) c += (s_start[q * 1024 + k] == b) ? 1 : 0;
        s_c4[q][b] = c;
    }
    __syncthreads();
    if (tid == 0){
        int acc = 0;
        for (int bb = 0; bb < Tt; ++bb){
            s_boff[bb] = acc;
            acc += s_c4[0][bb] + s_c4[1][bb] + s_c4[2][bb] + s_c4[3][bb];
        }
        s_boff[Tt] = acc;
    }
    __syncthreads();
    if (tid <= Tt) boff[tid] = s_boff[tid];
    int p = s_boff[b];
    if (q > 0) p += s_c4[0][b];
    if (q > 1) p += s_c4[1][b];
    if (q > 2) p += s_c4[2][b];
    for (int k = 0; k < 1024; ++k){
        int i = q * 1024 + k;
        if (s_start[i] == b) sidx[p++] = i;
    }
}

// ---------------- k_gbuckets: G_T[h][t] = sum_{i in bucket t} W1[h][i] ----------------
__global__ __launch_bounds__(256) void k_gbuckets(const float* __restrict__ W1,
        const int* __restrict__ boff, const int* __restrict__ sidx,
        float* __restrict__ G_T){
    __shared__ float rows[4][Nn]; // 64 KB
    int tid = threadIdx.x;
    int h0 = blockIdx.x * 4;
    for (int r = 0; r < 4; ++r){
        const float4* src = (const float4*)(W1 + (size_t)(h0 + r) * Nn);
        float4* dst = (float4*)rows[r];
        for (int j = tid; j < Nn / 4; j += 256) dst[j] = src[j];
    }
    __syncthreads();
    int t = tid;
    int b0 = boff[t], b1 = boff[t + 1];
    float s0 = 0.f, s1 = 0.f, s2 = 0.f, s3 = 0.f;
    for (int k = b0; k < b1; ++k){
        int i = sidx[k];
        s0 += rows[0][i]; s1 += rows[1][i]; s2 += rows[2][i]; s3 += rows[3][i];
    }
    G_T[(size_t)(h0 + 0) * Tt + t] = s0;
    G_T[(size_t)(h0 + 1) * Tt + t] = s1;
    G_T[(size_t)(h0 + 2) * Tt + t] = s2;
    G_T[(size_t)(h0 + 3) * Tt + t] = s3;
}

// ---------------- k_c1M: fused window-sum + M-scan + c1T transpose + r1 init ----------------
__global__ __launch_bounds__(256) void k_c1M(const float* __restrict__ G_T,
        float* __restrict__ c1T, float* __restrict__ M,
        float* __restrict__ r1pre, float* __restrict__ o_r1){
    __shared__ float tile[32][Tt + 1];
    __shared__ float c1s[32][Tt + 1];
    const int tid = threadIdx.x;
    const int h0 = blockIdx.x * 32;
    for (int r = 0; r < 32; ++r) tile[r][tid] = G_T[(size_t)(h0 + r) * Tt + tid];
    __syncthreads();
    {
        int hs = tid & 31, ts = tid >> 5;
        for (int tb = 0; tb < 32; ++tb){
            int t = tb * 8 + ts;
            int lo = (t - 7 < 0) ? 0 : t - 7;
            float s = 0.f;
            for (int u = lo; u <= t; ++u) s += tile[hs][u];
            c1s[hs][t] = s;
        }
    }
    __syncthreads();
    if (tid < 32){
        float m = 0.f;
        for (int t = 0; t < Tt; ++t){
            m = __fadd_rn(__fmul_rn(0.9f, m), c1s[tid][t]);
            M[(size_t)t * Hn + h0 + tid] = m;
        }
        r1pre[h0 + tid] = 0.f;
        o_r1[h0 + tid] = 256.f;
    }
    {
        int hr = tid >> 3, qq = tid & 7;
        float* drow = c1T + (size_t)(h0 + hr) * Tt + qq * 32;
        for (int k = 0; k < 8; ++k){
            float4 v = make_float4(c1s[hr][qq*32 + 4*k], c1s[hr][qq*32 + 4*k + 1],
                                   c1s[hr][qq*32 + 4*k + 2], c1s[hr][qq*32 + 4*k + 3]);
            ((float4*)drow)[k] = v;
        }
    }
}

// ---------------- k_sel: exact 128th-largest radix-select + candidate compaction ----------------
__global__ __launch_bounds__(256) void k_sel(const float* __restrict__ M,
        float2* __restrict__ cand, int* __restrict__ cnt){
    const int t = blockIdx.x, tid = threadIdx.x;
    __shared__ float s_row[Hn];        // 32 KB
    __shared__ unsigned s_hist[256];
    __shared__ unsigned s_suf[256];
    __shared__ unsigned s_pref;
    __shared__ int s_rank;
    __shared__ int s_cnt;
    __shared__ float2 s_list[CAP];
    {
        const float4* src = (const float4*)(M + (size_t)t * Hn);
        float4* d4 = (float4*)s_row;
        for (int j = tid; j < Hn / 4; j += 256) d4[j] = src[j];
    }
    if (tid == 0){ s_pref = 0u; s_rank = 128; s_cnt = 0; }
    __syncthreads();
#pragma unroll
    for (int b = 3; b >= 0; --b){
        s_hist[tid] = 0u;
        __syncthreads();
        unsigned pref = s_pref;
        int r = s_rank;
        for (int k = 0; k < 32; ++k){
            unsigned u = __float_as_uint(s_row[tid + (k << 8)]);
            bool match = (b == 3) ? true : ((u >> (((b + 1) & 3) * 8 + ((b==3)?0:8*0))) == pref);
            // compile-time b: for b<3, shift = (b+1)*8
            if (b < 3) match = ((u >> ((b + 1) * 8)) == pref);
            if (match) atomicAdd(&s_hist[(u >> (b * 8)) & 255], 1u);
        }
        __syncthreads();
        s_suf[tid] = s_hist[tid];
        __syncthreads();
#pragma unroll
        for (int off = 1; off < 256; off <<= 1){
            unsigned v = (tid + off < 256) ? s_suf[tid + off] : 0u;
            __syncthreads();
            s_suf[tid] += v;
            __syncthreads();
        }
        unsigned above = s_suf[tid] - s_hist[tid];
        if ((int)above < r && r <= (int)s_suf[tid]){
            s_pref = (pref << 8) | (unsigned)tid;
            s_rank = r - (int)above;
        }
        __syncthreads();
    }
    unsigned V = s_pref;
    for (int k = 0; k < 32; ++k){
        int i = tid + (k << 8);
        unsigned u = __float_as_uint(s_row[i]);
        if (u >= V){
            int p = atomicAdd(&s_cnt, 1);
            if (p < CAP) s_list[p] = make_float2(s_row[i], __int_as_float(i));
        }
    }
    __syncthreads();
    int c = s_cnt;
    if (tid == 0) cnt[t] = (c > CAP) ? -1 : c;
    int mn = (c > CAP) ? 0 : c;
    for (int i = tid; i < mn; i += 256)
        cand[(size_t)t * CAP + i] = s_list[i];
}

// ---------------- k_wta1: single-wave serial WTA, all state in registers ----------------
__global__ __launch_bounds__(64, 1) void k_wta1(
        const float* __restrict__ M, const float* __restrict__ c1T,
        const float2* __restrict__ cand, const int* __restrict__ cnt,
        const float* __restrict__ thr1,
        float* __restrict__ r1pre, float* __restrict__ o_r1,
        int* __restrict__ j1s, int* __restrict__ mh, int* __restrict__ nRout){
    const int lane = threadIdx.x;
    int   sh0=-1,sh1=-1,sh2=-1,sh3=-1;
    float sm0=0.f,sm1=0.f,sm2=0.f,sm3=0.f;
    float st0=0.f,st1=0.f,st2=0.f,st3=0.f;
    int   ss0=0,ss1=0,ss2=0,ss3=0;
    float sr0=0.f,sr1=0.f,sr2=0.f,sr3=0.f;
    float4 z4 = make_float4(0.f,0.f,0.f,0.f);
    float4 dA0=z4,dA1=z4,dA2=z4,dA3=z4,dB0=z4,dB1=z4,dB2=z4,dB3=z4;
    unsigned bm0=0,bm1=0,bm2=0,bm3=0;
    int nR = 0;

    float2 cA[4][3], cB[4][3];
    float  tA[4][3];
    int    nA[4], nB[4];

#pragma unroll
    for (int jj = 0; jj < 4; ++jj){
#pragma unroll
        for (int cc = 0; cc < 3; ++cc){
            cA[jj][cc] = cand[(size_t)jj * CAP + (cc << 6) + lane];
            cB[jj][cc] = cand[(size_t)(4 + jj) * CAP + (cc << 6) + lane];
        }
        nA[jj] = cnt[jj]; nB[jj] = cnt[4 + jj];
    }
#pragma unroll
    for (int jj = 0; jj < 4; ++jj)
#pragma unroll
        for (int cc = 0; cc < 3; ++cc){
            int ok = ((cc << 6) + lane) < nA[jj];
            int ci = __float_as_int(cA[jj][cc].y) & 8191;
            tA[jj][cc] = ok ? thr1[ci] : 0.f;
        }

    for (int g = 0; g < 64; ++g){
#pragma unroll
        for (int jj = 0; jj < 4; ++jj){
            const int t = (g << 2) + jj;
            ull best = 0ull;
#define UPD(i) if (sh##i >= 0){ \
                float dv = (jj==0)?dA##i.x:(jj==1)?dA##i.y:(jj==2)?dA##i.z:dA##i.w; \
                sm##i = __fadd_rn(__fmul_rn(0.9f, sm##i), dv); \
                ull kk = KEY(sm##i, sh##i); if (kk > best) best = kk; }
            UPD(0) UPD(1) UPD(2) UPD(3)
#undef UPD
            const int cn = nA[jj];
            int nmflag = 0;
#pragma unroll
            for (int cc = 0; cc < 3; ++cc){
                int ci = __float_as_int(cA[jj][cc].y);
                int wi = (ci >> 5) & 255;
                int ln = wi & 63, rg = wi >> 6;
                unsigned w0=__shfl(bm0,ln), w1=__shfl(bm1,ln), w2=__shfl(bm2,ln), w3=__shfl(bm3,ln);
                unsigned wd = rg==0?w0:rg==1?w1:rg==2?w2:w3;
                int isM = (wd >> (ci & 31)) & 1;
                int ok = ((cc << 6) + lane) < cn;
                if (ok && !isM){
                    nmflag |= (1 << cc);
                    ull kk = KEY(cA[jj][cc].x, ci);
                    if (kk > best) best = kk;
                }
            }
            ull anyNM = __ballot(nmflag != 0);
            if (anyNM == 0ull){
                // exact fallback: full-row scan over non-members
                const float* Mrow = M + (size_t)t * Hn;
                for (int k2 = 0; k2 < 128; ++k2){
                    int i = (k2 << 6) | lane;
                    float x = Mrow[i];
                    int wi = i >> 5;
                    int ln = wi & 63, rg = wi >> 6;
                    unsigned w0=__shfl(bm0,ln), w1=__shfl(bm1,ln), w2=__shfl(bm2,ln), w3=__shfl(bm3,ln);
                    unsigned wd = rg==0?w0:rg==1?w1:rg==2?w2:w3;
                    if (!((wd >> (i & 31)) & 1u)){
                        ull kk = KEY(x, i); if (kk > best) best = kk;
                    }
                }
            }
            ull wk = best;
#pragma unroll
            for (int off = 1; off < 64; off <<= 1){
                ull o = shflxor64(wk, off);
                if (o > wk) wk = o;
            }
            const int wh = KIDX(wk);
            const float wv = KVAL(wk);
            int m0=(sh0==wh), m1=(sh1==wh), m2=(sh2==wh), m3=(sh3==wh);
            ull memMask = __ballot(m0 | m1 | m2 | m3);
            int fire;
            if (memMask != 0ull){
                int fflag = 0, jsl = -1;
#define DSL(i) if (m##i){ int nup = t - ss##i - 1; float te = th_lazy2(st##i, 150.f, 400.f, nup); \
                  if (wv > te){ fflag = 1; sm##i = 0.f; \
                      st##i = fminf(fmaxf(__fadd_rn(__fsub_rn(te,0.05f),5.0f),150.f),400.f); ss##i = t; \
                      jsl = (i << 6) | lane; } }
                DSL(0) DSL(1) DSL(2) DSL(3)
#undef DSL
                ull fm = __ballot(fflag);
                fire = (fm != 0ull);
                if (fire){ if (fflag) j1s[t] = jsl; }
                else if (lane == 0) j1s[t] = -1;
            } else {
                float teff = 0.f;
                int prop = 0;
#pragma unroll
                for (int cc = 0; cc < 3; ++cc){
                    if ((nmflag >> cc) & 1){
                        int ci = __float_as_int(cA[jj][cc].y);
                        if (ci == wh){ teff = th_lazy2(tA[jj][cc], 150.f, 400.f, t); prop = 1; }
                    }
                }
                ull pm = __ballot(prop);
                float te_b;
                if (pm != 0ull){
                    int pl = __ffsll(pm) - 1;
                    int ff = (prop && (wv > teff)) ? 1 : 0;
                    ull fm = __ballot(ff);
                    fire = (fm != 0ull);
                    te_b = __shfl(teff, pl);
                } else {
                    float th0v = thr1[wh];
                    te_b = th_lazy2(th0v, 150.f, 400.f, t);
                    fire = (wv > te_b) ? 1 : 0;
                }
                if (fire){
                    float thnew = fminf(fmaxf(__fadd_rn(__fsub_rn(te_b,0.05f),5.0f),150.f),400.f);
                    if (lane == (nR & 63)){
                        const float4* crow = (const float4*)(c1T + (size_t)wh * Tt);
                        int g1 = (g + 1 < 64) ? g + 1 : 63;
                        int srg = nR >> 6;
#define JN(i) { sh##i = wh; sm##i = 0.f; st##i = thnew; ss##i = t; sr##i = (float)(t+1); \
                dA##i = crow[g]; dB##i = crow[g1]; }
                        if (srg == 0){ JN(0) } else if (srg == 1){ JN(1) }
                        else if (srg == 2){ JN(2) } else { JN(3) }
#undef JN
                        j1s[t] = nR;
                        mh[nR] = wh;
                    }
                    {
                        int wi = wh >> 5;
                        if (lane == (wi & 63)){
                            unsigned bit = 1u << (wh & 31);
                            int rg = wi >> 6;
                            if (rg==0) bm0|=bit; else if (rg==1) bm1|=bit;
                            else if (rg==2) bm2|=bit; else bm3|=bit;
                        }
                    }
                    nR++;
                } else {
                    if (lane == 0) j1s[t] = -1;
                }
            }
        } // jj
        if (g < 63){
            int g2 = (g + 2 < 64) ? g + 2 : 63;
#define RT(i) { dA##i = dB##i; if (sh##i >= 0) dB##i = ((const float4*)(c1T + (size_t)sh##i * Tt))[g2]; }
            RT(0) RT(1) RT(2) RT(3)
#undef RT
#pragma unroll
            for (int jj = 0; jj < 4; ++jj){
#pragma unroll
                for (int cc = 0; cc < 3; ++cc) cA[jj][cc] = cB[jj][cc];
                nA[jj] = nB[jj];
            }
            if (g < 62){
#pragma unroll
                for (int jj = 0; jj < 4; ++jj){
#pragma unroll
                    for (int cc = 0; cc < 3; ++cc)
                        cB[jj][cc] = cand[(size_t)((g + 2) * 4 + jj) * CAP + (cc << 6) + lane];
                    nB[jj] = cnt[(g + 2) * 4 + jj];
                }
            }
#pragma unroll
            for (int jj = 0; jj < 4; ++jj)
#pragma unroll
                for (int cc = 0; cc < 3; ++cc){
                    int ok = ((cc << 6) + lane) < nA[jj];
                    int ci = __float_as_int(cA[jj][cc].y) & 8191;
                    tA[jj][cc] = ok ? thr1[ci] : 0.f;
                }
        }
    } // g
#define WB(i) if (sh##i >= 0){ r1pre[sh##i] = sr##i; o_r1[sh##i] = sr##i; }
    WB(0) WB(1) WB(2) WB(3)
#undef WB
    if (lane == 0) *nRout = nR;
}

// ---------------- k_colg: gather distinct member columns of W2 ----------------
__global__ __launch_bounds__(256) void k_colg(const float* __restrict__ W2,
        const int* __restrict__ mh, const int* __restrict__ nRout,
        float* __restrict__ colv){
    int slot = blockIdx.x;
    if (slot >= *nRout) return;
    int h = mh[slot];
    int tid = threadIdx.x;
    float* dst = colv + (size_t)slot * Nn;
    for (int n = tid; n < Nn; n += 256) dst[n] = W2[(size_t)n * Hn + h];
}

// ---------------- k_lif2: layer 2 per-neuron LIF, ballot spike masks ----------------
__global__ __launch_bounds__(64) void k_lif2(const float* __restrict__ colv,
        const int* __restrict__ j1s, const float* __restrict__ thr2,
        float* __restrict__ o_r2, ull* __restrict__ spkb, unsigned* __restrict__ anyv){
    __shared__ int s_j[Tt];
    int lane = threadIdx.x, blk = blockIdx.x;
    for (int i = lane; i < Tt; i += 64) s_j[i] = j1s[i];
    __syncthreads();
    int n = blk * 64 + lane;
    float tv = thr2[n], m = 0.f, rp = 0.f;
    for (int t = 0; t < Tt; ++t){
        int s = s_j[t];
        float u = (s >= 0) ? colv[(size_t)s * Nn + n] : 0.f;
        m = __fadd_rn(__fmul_rn(0.8f, m), u);
        int f = 0;
        if (m > tv){
            m = __fsub_rn(m, tv);
            if (rp == 0.f) rp = (float)(t + 1);
            f = 1;
        }
        ull mask = __ballot(f);
        if (lane == 0){
            spkb[t * 64 + blk] = mask;
            if (mask) atomicOr(&anyv[t], 1u);
        }
    }
    o_r2[n] = (rp == 0.f) ? 256.f : rp;
}

// ---------------- k_w3t: W3T[n][c] = W3[c][n] ----------------
__global__ __launch_bounds__(256) void k_w3t(const float* __restrict__ W3,
                                             float* __restrict__ W3T){
    __shared__ float tl[64][65];
    int bx = blockIdx.x & 63, by = blockIdx.x >> 6;
    int n0 = bx * 64, c0 = by * 64;
    int tid = threadIdx.x;
    for (int e = tid; e < 64 * 64; e += 256){
        int r = e >> 6, cc = e & 63;
        tl[r][cc] = W3[(size_t)(c0 + r) * Nn + n0 + cc];
    }
    __syncthreads();
    for (int e = tid; e < 64 * 64; e += 256){
        int rn = e >> 6, cc = e & 63;
        W3T[(size_t)(n0 + rn) * Cn + c0 + cc] = tl[cc][rn];
    }
}

// ---------------- k_sim3: layer 3 WTA; skips exact-zero quiet steps ----------------
__global__ __launch_bounds__(128, 1) void k_sim3(const ull* __restrict__ spkb,
        const unsigned* __restrict__ anyv, const float* __restrict__ W3T,
        const float* __restrict__ thr3, float* __restrict__ o_r3){
    int tid = threadIdx.x, lane = tid & 63, w = tid >> 6;
    __shared__ unsigned s_any[Tt];
    __shared__ ull s_r2[2];
    __shared__ int s_fire;
    for (int i = tid; i < Tt; i += 128) s_any[i] = anyv[i];
    float m = 0.f, th0 = thr3[tid], rp = 0.f, thv = 0.f;
    int ts = -1, zero = 1;
    __syncthreads();
    for (int t = 0; t < Tt; ++t){
        if (zero && s_any[t] == 0u) continue;
        float d = 0.f;
        if (s_any[t]){
            for (int ww = 0; ww < 64; ++ww){
                ull bits = spkb[t * 64 + ww];
                while (bits){
                    int b2 = __ffsll(bits) - 1;
                    bits &= bits - 1;
                    d = __fadd_rn(d, W3T[(size_t)(ww * 64 + b2) * Cn + tid]);
                }
            }
        }
        m = __fadd_rn(__fmul_rn(0.9f, m), d);
        ull k = KEY(m, tid);
#pragma unroll
        for (int off = 32; off >= 1; off >>= 1){
            ull o = __shfl_down(k, off);
            if (o > k) k = o;
        }
        if (lane == 0) s_r2[w] = k;
        __syncthreads();
        ull wk = s_r2[0] > s_r2[1] ? s_r2[0] : s_r2[1];
        int wc = KIDX(wk);
        float wv = KVAL(wk);
        if (tid == wc){
            float te = (ts < 0) ? th_lazy2(th0, 50.f, 200.f, t)
                                : th_lazy2(thv, 50.f, 200.f, t - ts - 1);
            int f = (wv > te) ? 1 : 0;
            s_fire = f;
            if (f){
                thv = fminf(fmaxf(__fadd_rn(__fsub_rn(te, 0.05f), 5.0f), 50.f), 200.f);
                ts = t;
                if (rp == 0.f) rp = (float)(t + 1);
            }
        }
        __syncthreads();
        if (s_fire){ m = 0.f; zero = 1; }
        else zero = 0;
        __syncthreads();
    }
    o_r3[tid] = (rp == 0.f) ? 256.f : rp;
}

// ---------------- k_scalars: zeta/rho/error + factored exp tables ----------------
__global__ __launch_bounds__(1024) void k_scalars(const float* __restrict__ image,
        const float* __restrict__ r1pre, const float* __restrict__ o_r1,
        const float* __restrict__ o_r2,
        float* __restrict__ zeta, float* __restrict__ rho,
        float* __restrict__ imgt, float* __restrict__ eiP, float* __restrict__ eiM,
        float* __restrict__ Pv, float* __restrict__ Qv,
        float* __restrict__ E2P, float* __restrict__ E2M,
        float* __restrict__ o_err, float* __restrict__ o_es){
    int tid = threadIdx.x;
    for (int h = tid; h < Hn; h += 1024){
        float r1f = o_r1[h];
        float mask = (r1pre[h] != 0.f) ? 1.f : 0.f;
        float z = __fmul_rn(__fmul_rn(__fsub_rn(256.f, r1f), mask), 0.00390625f);
        zeta[h] = z;
        Pv[h] = __expf(r1f * 0.05f) * z;
        Qv[h] = __expf(-r1f * 0.05f) * z;
    }
    float acc = 0.f;
    for (int n = tid; n < Nn; n += 1024){
        float img = __fmul_rn(256.f, image[n]);
        float r2f = o_r2[n];
        float e = __fmul_rn(__fsub_rn(img, __fsub_rn(r2f, 4.0f)), 0.00390625f);
        o_err[n] = e;
        rho[n] = __fadd_rn(__fmul_rn(__fsub_rn(__fsub_rn(r2f, 4.0f), img), 0.00390625f), 0.15f);
        imgt[n] = img;
        eiP[n] = __expf(img * 0.05f);
        eiM[n] = __expf(-img * 0.05f);
        E2P[n] = __expf(r2f * 0.05f);
        E2M[n] = __expf(-r2f * 0.05f);
        acc = __fadd_rn(acc, __fmul_rn(e, e));
    }
    __shared__ float red[16];
    for (int off = 32; off >= 1; off >>= 1) acc += __shfl_down(acc, off);
    int lane = tid & 63, w = tid >> 6;
    if (lane == 0) red[w] = acc;
    __syncthreads();
    if (tid == 0){
        float s = 0.f;
        for (int q = 0; q < 16; ++q) s += red[q];
        *o_es = s;
    }
}

// ---------------- STDP weight updates (factored exp, float4 streams) ----------------
__global__ __launch_bounds__(256) void k_w1new(const float* __restrict__ W1,
        const float* __restrict__ imgt, const float* __restrict__ eiP,
        const float* __restrict__ eiM, const float* __restrict__ r1pre,
        const float* __restrict__ o_r1, float* __restrict__ o_W1){
    int h = blockIdx.x, tid = threadIdx.x;
    float r1f = o_r1[h];
    bool msk = (r1pre[h] != 0.f);
    float a = 0.01f * __expf(-r1f * 0.05f);
    float b = 0.01f * __expf( r1f * 0.05f);
    const float4* src = (const float4*)(W1 + (size_t)h * Nn);
    float4* dst = (float4*)(o_W1 + (size_t)h * Nn);
    const float4* ig = (const float4*)imgt;
    const float4* p4 = (const float4*)eiP;
    const float4* m4 = (const float4*)eiM;
    for (int i = tid; i < Nn / 4; i += 256){
        float4 s = src[i];
        if (msk){
            float4 im = ig[i], pp = p4[i], mm = m4[i];
            s.x += (r1f >= im.x) ? a * pp.x : -(b * mm.x);
            s.y += (r1f >= im.y) ? a * pp.y : -(b * mm.y);
            s.z += (r1f >= im.z) ? a * pp.z : -(b * mm.z);
            s.w += (r1f >= im.w) ? a * pp.w : -(b * mm.w);
        } else {
            s.x += 0.01f; s.y += 0.01f; s.z += 0.01f; s.w += 0.01f;
        }
        dst[i] = s;
    }
}

__global__ __launch_bounds__(256) void k_w2new(const float* __restrict__ W2,
        const float* __restrict__ o_r1, const float* __restrict__ Pv,
        const float* __restrict__ Qv, const float* __restrict__ o_r2,
        const float* __restrict__ rho, float* __restrict__ o_W2){
    int n = blockIdx.x, tid = threadIdx.x;
    float r2f = o_r2[n], rh = rho[n];
    float A = 0.01f * rh * __expf(-r2f * 0.05f);
    float B = 0.01f * rh * __expf( r2f * 0.05f);
    const float4* src = (const float4*)(W2 + (size_t)n * Hn);
    float4* dst = (float4*)(o_W2 + (size_t)n * Hn);
    const float4* r14 = (const float4*)o_r1;
    const float4* p4 = (const float4*)Pv;
    const float4* q4 = (const float4*)Qv;
    for (int i = tid; i < Hn / 4; i += 256){
        float4 s = src[i]; float4 rv = r14[i]; float4 pp = p4[i]; float4 qq = q4[i];
        s.x = clamp01(s.x + ((r2f >= rv.x) ? A * pp.x : -(B * qq.x)));
        s.y = clamp01(s.y + ((r2f >= rv.y) ? A * pp.y : -(B * qq.y)));
        s.z = clamp01(s.z + ((r2f >= rv.z) ? A * pp.z : -(B * qq.z)));
        s.w = clamp01(s.w + ((r2f >= rv.w) ? A * pp.w : -(B * qq.w)));
        dst[i] = s;
    }
}

__global__ __launch_bounds__(256) void k_w3new(const float* __restrict__ W3,
        const float* __restrict__ o_r2, const float* __restrict__ E2P,
        const float* __restrict__ E2M, const float* __restrict__ o_r3,
        float* __restrict__ o_W3){
    int c = blockIdx.x, tid = threadIdx.x;
    float r3f = o_r3[c];
    float a = 0.01f * __expf(-r3f * 0.05f);
    float b = 0.01f * __expf( r3f * 0.05f);
    const float4* src = (const float4*)(W3 + (size_t)c * Nn);
    float4* dst = (float4*)(o_W3 + (size_t)c * Nn);
    const float4* r24 = (const float4*)o_r2;
    const float4* p4 = (const float4*)E2P;
    const float4* m4 = (const float4*)E2M;
    for (int i = tid; i < Nn / 4; i += 256){
        float4 s = src[i]; float4 rv = r24[i]; float4 pp = p4[i]; float4 mm = m4[i];
        s.x += (r3f >= rv.x) ? a * pp.x : -(b * mm.x);
        s.y += (r3f >= rv.y) ? a * pp.y : -(b * mm.y);
        s.z += (r3f >= rv.z) ? a * pp.z : -(b * mm.z);
        s.w += (r3f >= rv.w) ? a * pp.w : -(b * mm.w);
        dst[i] = s;
    }
}

extern "C" void kernel_launch(void* const* d_in, const int* in_sizes, int n_in,
                              void* d_out, int out_size, void* d_ws, size_t ws_size,
                              hipStream_t stream){
    const float* image = (const float*)d_in[0];
    const float* W1   = (const float*)d_in[1];
    const float* W2   = (const float*)d_in[2];
    const float* W3   = (const float*)d_in[3];
    const float* thr1 = (const float*)d_in[4];
    const float* thr2 = (const float*)d_in[5];
    const float* thr3 = (const float*)d_in[6];

    float* out  = (float*)d_out;
    float* o_err = out;                       // [4096]
    float* o_es  = out + 4096;                // [1]
    float* o_r1  = out + 4097;                // [8192]
    float* o_r2  = out + 12289;               // [4096]
    float* o_r3  = out + 16385;               // [128]
    float* o_W1  = out + 16513;               // [8192*4096]
    float* o_W2  = o_W1 + (size_t)Hn * Nn;    // [4096*8192]
    float* o_W3  = o_W2 + (size_t)Nn * Hn;    // [128*4096]

    float* ws = (float*)d_ws;
    float* G_T   = ws;                                  // H*T
    float* c1T   = G_T + (size_t)Hn * Tt;               // H*T
    float* M     = c1T + (size_t)Hn * Tt;               // T*H
    float* W3T   = M + (size_t)Tt * Hn;                 // N*C
    float* colv  = W3T + (size_t)Nn * Cn;               // 256*N
    float2* cand = (float2*)(colv + (size_t)256 * Nn);  // T*CAP float2
    float* fafter = (float*)(cand + (size_t)Tt * CAP);
    ull* spkb    = (ull*)fafter;                        // T*64 u64
    float* r1pre = (float*)(spkb + (size_t)Tt * 64);    // H
    float* zeta  = r1pre + Hn;                          // H
    float* rho   = zeta + Hn;                           // N
    float* imgt  = rho + Nn;                            // N
    float* eiP   = imgt + Nn;                           // N
    float* eiM   = eiP + Nn;                            // N
    float* Pv    = eiM + Nn;                            // H
    float* Qv    = Pv + Hn;                             // H
    float* E2P   = Qv + Hn;                             // N
    float* E2M   = E2P + Nn;                            // N
    int* boff  = (int*)(E2M + Nn);                      // T+1
    int* sidx  = boff + (Tt + 1);                       // N
    int* cnt   = sidx + Nn;                             // T
    int* j1s   = cnt + Tt;                              // T
    int* mh    = j1s + Tt;                              // T
    int* nRout = mh + Tt;                               // 1
    unsigned* anyv = (unsigned*)(nRout + 1);            // T

    k_prep<<<1, 1024, 0, stream>>>(image, boff, sidx, anyv);
    k_gbuckets<<<Hn / 4, 256, 0, stream>>>(W1, boff, sidx, G_T);
    k_c1M<<<Hn / 32, 256, 0, stream>>>(G_T, c1T, M, r1pre, o_r1);
    k_sel<<<Tt, 256, 0, stream>>>(M, cand, cnt);
    k_wta1<<<1, 64, 0, stream>>>(M, c1T, cand, cnt, thr1, r1pre, o_r1, j1s, mh, nRout);
    k_colg<<<256, 256, 0, stream>>>(W2, mh, nRout, colv);
    k_lif2<<<Nn / 64, 64, 0, stream>>>(colv, j1s, thr2, o_r2, spkb, anyv);
    k_w3t<<<128, 256, 0, stream>>>(W3, W3T);
    k_sim3<<<1, 128, 0, stream>>>(spkb, anyv, W3T, thr3, o_r3);
    k_scalars<<<1, 1024, 0, stream>>>(image, r1pre, o_r1, o_r2, zeta, rho,
                                      imgt, eiP, eiM, Pv, Qv, E2P, E2M, o_err, o_es);
    k_w1new<<<Hn, 256, 0, stream>>>(W1, imgt, eiP, eiM, r1pre, o_r1, o_W1);
    k_w2new<<<Nn, 256, 0, stream>>>(W2, o_r1, Pv, Qv, o_r2, rho, o_W2);
    k_w3new<<<Cn, 256, 0, stream>>>(W3, o_r2, E2P, E2M, o_r3, o_W3);
}

// Round 5
// 824.067 us; speedup vs baseline: 1.6941x; 1.0714x over previous
//
#include <hip/hip_runtime.h>
#include <cstdint>
#include <cstddef>

#define Hn 8192
#define Nn 4096
#define Cn 128
#define Tt 256
#define CAP 192

typedef unsigned long long ull;

__device__ __forceinline__ ull KEY(float v, int h){
    return ((ull)__float_as_uint(v) << 32) | (unsigned)(8191 - h);
}
__device__ __forceinline__ int KIDX(ull k){ return 8191 - (int)(k & 0xFFFFu); }
__device__ __forceinline__ float KVAL(ull k){ return __uint_as_float((unsigned)(k >> 32)); }

__device__ __forceinline__ ull shflxor64(ull x, int m){
    unsigned lo = (unsigned)x, hi = (unsigned)(x >> 32);
    lo = __shfl_xor(lo, m); hi = __shfl_xor(hi, m);
    return ((ull)hi << 32) | lo;
}

// th after nup clip-updates (decay -0.05 each) from base b, clamped [lo,hi]
__device__ __forceinline__ float th_lazy2(float b, float lo, float hi, int nup){
    if (nup <= 0) return b;
    float a = fminf(fmaxf(__fsub_rn(b, 0.05f), lo), hi);
    if (nup == 1) return a;
    return fmaxf(__fsub_rn(a, __fmul_rn(0.05f, (float)(nup - 1))), lo);
}

__device__ __forceinline__ float clamp01(float v){
    return fminf(fmaxf(v, 0.f), 1.f);
}

// ---------------- k_prep: start buckets + deterministic counting sort (1024 thr) ----------------
__global__ __launch_bounds__(1024) void k_prep(const float* __restrict__ image,
        int* __restrict__ boff, int* __restrict__ sidx, unsigned* __restrict__ anyv){
    __shared__ int s_start[Nn];
    __shared__ int s_c4[4][Tt];
    __shared__ int s_boff[Tt + 1];
    int tid = threadIdx.x;
    for (int i = tid; i < Nn; i += 1024)
        s_start[i] = (int)floorf(__fmul_rn(256.f, image[i]));
    if (tid < Tt) anyv[tid] = 0u;
    __syncthreads();
    int b = tid & 255, q = tid >> 8;
    {
        int c = 0;
        for (int k = 0; k < 1024; ++k) c += (s_start[q * 1024 + k] == b) ? 1 : 0;
        s_c4[q][b] = c;
    }
    __syncthreads();
    if (tid == 0){
        int acc = 0;
        for (int bb = 0; bb < Tt; ++bb){
            s_boff[bb] = acc;
            acc += s_c4[0][bb] + s_c4[1][bb] + s_c4[2][bb] + s_c4[3][bb];
        }
        s_boff[Tt] = acc;
    }
    __syncthreads();
    if (tid <= Tt) boff[tid] = s_boff[tid];
    int p = s_boff[b];
    if (q > 0) p += s_c4[0][b];
    if (q > 1) p += s_c4[1][b];
    if (q > 2) p += s_c4[2][b];
    for (int k = 0; k < 1024; ++k){
        int i = q * 1024 + k;
        if (s_start[i] == b) sidx[p++] = i;
    }
}

// ---------------- k_gbuckets: G_T[h][t] = sum_{i in bucket t} W1[h][i] ----------------
__global__ __launch_bounds__(256) void k_gbuckets(const float* __restrict__ W1,
        const int* __restrict__ boff, const int* __restrict__ sidx,
        float* __restrict__ G_T){
    __shared__ float rows[4][Nn]; // 64 KB
    int tid = threadIdx.x;
    int h0 = blockIdx.x * 4;
    for (int r = 0; r < 4; ++r){
        const float4* src = (const float4*)(W1 + (size_t)(h0 + r) * Nn);
        float4* dst = (float4*)rows[r];
        for (int j = tid; j < Nn / 4; j += 256) dst[j] = src[j];
    }
    __syncthreads();
    int t = tid;
    int b0 = boff[t], b1 = boff[t + 1];
    float s0 = 0.f, s1 = 0.f, s2 = 0.f, s3 = 0.f;
    for (int k = b0; k < b1; ++k){
        int i = sidx[k];
        s0 += rows[0][i]; s1 += rows[1][i]; s2 += rows[2][i]; s3 += rows[3][i];
    }
    G_T[(size_t)(h0 + 0) * Tt + t] = s0;
    G_T[(size_t)(h0 + 1) * Tt + t] = s1;
    G_T[(size_t)(h0 + 2) * Tt + t] = s2;
    G_T[(size_t)(h0 + 3) * Tt + t] = s3;
}

// ---------------- k_c1M: fused window-sum + M-scan + c1T transpose + r1 init ----------------
__global__ __launch_bounds__(256) void k_c1M(const float* __restrict__ G_T,
        float* __restrict__ c1T, float* __restrict__ M,
        float* __restrict__ r1pre, float* __restrict__ o_r1){
    __shared__ float tile[32][Tt + 1];
    __shared__ float c1s[32][Tt + 1];
    const int tid = threadIdx.x;
    const int h0 = blockIdx.x * 32;
    for (int r = 0; r < 32; ++r) tile[r][tid] = G_T[(size_t)(h0 + r) * Tt + tid];
    __syncthreads();
    {
        int hs = tid & 31, ts = tid >> 5;
        for (int tb = 0; tb < 32; ++tb){
            int t = tb * 8 + ts;
            int lo = (t - 7 < 0) ? 0 : t - 7;
            float s = 0.f;
            for (int u = lo; u <= t; ++u) s += tile[hs][u];
            c1s[hs][t] = s;
        }
    }
    __syncthreads();
    if (tid < 32){
        float m = 0.f;
        for (int t = 0; t < Tt; ++t){
            m = __fadd_rn(__fmul_rn(0.9f, m), c1s[tid][t]);
            M[(size_t)t * Hn + h0 + tid] = m;
        }
        r1pre[h0 + tid] = 0.f;
        o_r1[h0 + tid] = 256.f;
    }
    {
        int hr = tid >> 3, qq = tid & 7;
        float* drow = c1T + (size_t)(h0 + hr) * Tt + qq * 32;
        for (int k = 0; k < 8; ++k){
            float4 v = make_float4(c1s[hr][qq*32 + 4*k], c1s[hr][qq*32 + 4*k + 1],
                                   c1s[hr][qq*32 + 4*k + 2], c1s[hr][qq*32 + 4*k + 3]);
            ((float4*)drow)[k] = v;
        }
    }
}

// ---------------- k_sel: exact rank-CAP radix-select + candidate list with th ----------------
__global__ __launch_bounds__(256) void k_sel(const float* __restrict__ M,
        const float* __restrict__ thr1, float4* __restrict__ cand){
    const int t = blockIdx.x, tid = threadIdx.x;
    __shared__ float s_row[Hn];        // 32 KB
    __shared__ unsigned s_hist[256];
    __shared__ unsigned s_suf[256];
    __shared__ unsigned s_pref;
    __shared__ int s_rank;
    __shared__ int s_cnt;
    __shared__ int s_idx[CAP + 64];
    {
        const float4* src = (const float4*)(M + (size_t)t * Hn);
        float4* d4 = (float4*)s_row;
        for (int j = tid; j < Hn / 4; j += 256) d4[j] = src[j];
    }
    if (tid == 0){ s_pref = 0u; s_rank = CAP; s_cnt = 0; }
    __syncthreads();
#pragma unroll
    for (int b = 3; b >= 0; --b){
        s_hist[tid] = 0u;
        __syncthreads();
        unsigned pref = s_pref;
        int r = s_rank;
        for (int k = 0; k < 32; ++k){
            unsigned u = __float_as_uint(s_row[tid + (k << 8)]);
            bool match = (b == 3) ? true : ((u >> ((b + 1) * 8)) == pref);
            if (match) atomicAdd(&s_hist[(u >> (b * 8)) & 255], 1u);
        }
        __syncthreads();
        s_suf[tid] = s_hist[tid];
        __syncthreads();
#pragma unroll
        for (int off = 1; off < 256; off <<= 1){
            unsigned v = (tid + off < 256) ? s_suf[tid + off] : 0u;
            __syncthreads();
            s_suf[tid] += v;
            __syncthreads();
        }
        unsigned above = s_suf[tid] - s_hist[tid];
        if ((int)above < r && r <= (int)s_suf[tid]){
            s_pref = (pref << 8) | (unsigned)tid;
            s_rank = r - (int)above;
        }
        __syncthreads();
    }
    unsigned V = s_pref;
    for (int k = 0; k < 32; ++k){
        int i = tid + (k << 8);
        unsigned u = __float_as_uint(s_row[i]);
        if (u >= V){
            int p = atomicAdd(&s_cnt, 1);
            if (p < CAP + 64) s_idx[p] = i;
        }
    }
    __syncthreads();
    int c = s_cnt;
    bool ovf = (c > CAP);
    float vV = __uint_as_float(V);
    for (int i = tid; i < CAP; i += 256){
        float4 e;
        if (ovf){
            e = make_float4(-2.f, 0.f, 0.f, 3.4e38f);
        } else if (i < c){
            int ix = s_idx[i];
            e = make_float4(s_row[ix], __int_as_float(ix),
                            th_lazy2(thr1[ix], 150.f, 400.f, t), vV);
        } else {
            e = make_float4(-1.f, 0.f, 0.f, vV);
        }
        cand[(size_t)t * CAP + i] = e;
    }
}

// ---------------- k_wta1: single-wave serial WTA; LDS membership, no barriers ----------------
__global__ __launch_bounds__(64, 1) void k_wta1(
        const float* __restrict__ M, const float* __restrict__ c1T,
        const float4* __restrict__ cand, const float* __restrict__ thr1,
        float* __restrict__ r1pre, float* __restrict__ o_r1,
        int* __restrict__ j1s, int* __restrict__ mh, int* __restrict__ nRout){
    const int lane = threadIdx.x;
    __shared__ unsigned char s_memb[Hn];   // 8 KB
    {
        uint4 z = make_uint4(0u, 0u, 0u, 0u);
        uint4* p = (uint4*)s_memb;
        for (int i = lane; i < Hn / 16; i += 64) p[i] = z;
    }
    int   sh0=-1,sh1=-1,sh2=-1,sh3=-1;
    float sm0=0.f,sm1=0.f,sm2=0.f,sm3=0.f;
    float st0=0.f,st1=0.f,st2=0.f,st3=0.f;
    int   ss0=0,ss1=0,ss2=0,ss3=0;
    float sr0=0.f,sr1=0.f,sr2=0.f,sr3=0.f;
    float4 z4 = make_float4(0.f,0.f,0.f,0.f);
    float4 dA0=z4,dA1=z4,dA2=z4,dA3=z4,dB0=z4,dB1=z4,dB2=z4,dB3=z4;
    int nR = 0;

    float4 cA0 = cand[lane],            cA1 = cand[64 + lane],       cA2 = cand[128 + lane];
    float4 cB0 = cand[CAP + lane],      cB1 = cand[CAP + 64 + lane], cB2 = cand[CAP + 128 + lane];
    int mb0 = 0, mb1 = 0, mb2 = 0;      // membership flags for current step's candidates

    for (int t = 0; t < Tt; ++t){
        const int g = t >> 2, jj = t & 3;
        ull best = 0ull;
#define UPD(i) if (sh##i >= 0){ \
            float dv = (jj==0)?dA##i.x:(jj==1)?dA##i.y:(jj==2)?dA##i.z:dA##i.w; \
            sm##i = __fadd_rn(__fmul_rn(0.9f, sm##i), dv); \
            ull kk = KEY(sm##i, sh##i); if (kk > best) best = kk; }
        UPD(0) UPD(1) UPD(2) UPD(3)
#undef UPD
        const int i0 = __float_as_int(cA0.y), i1 = __float_as_int(cA1.y), i2 = __float_as_int(cA2.y);
        const int nm0 = (cA0.x >= 0.f) && !mb0;
        const int nm1 = (cA1.x >= 0.f) && !mb1;
        const int nm2 = (cA2.x >= 0.f) && !mb2;
        if (nm0){ ull kk = KEY(cA0.x, i0); if (kk > best) best = kk; }
        if (nm1){ ull kk = KEY(cA1.x, i1); if (kk > best) best = kk; }
        if (nm2){ ull kk = KEY(cA2.x, i2); if (kk > best) best = kk; }
        ull anyNM = __ballot(nm0 | nm1 | nm2);
        ull wk = best;
#pragma unroll
        for (int off = 1; off < 64; off <<= 1){
            ull o = shflxor64(wk, off);
            if (o > wk) wk = o;
        }
        int didFB = 0, skip = 0;
        if (anyNM == 0ull){
            float v192 = cA0.w;
            if (KVAL(wk) >= v192){
                // best member dominates all unlisted non-members: exact
            } else if (t > 0 && v192 < 150.f){
                skip = 1;   // nothing can cross threshold this step
            } else {
                // rare exact fallback: full-row scan over non-members
                ull fk = wk;
                const float4* Mrow4 = (const float4*)(M + (size_t)t * Hn);
                for (int q = 0; q < 32; ++q){
                    int e = q * 64 + lane;
                    float4 mv = Mrow4[e];
                    int ib = e * 4;
                    if (!s_memb[ib+0]){ ull kk = KEY(mv.x, ib+0); if (kk > fk) fk = kk; }
                    if (!s_memb[ib+1]){ ull kk = KEY(mv.y, ib+1); if (kk > fk) fk = kk; }
                    if (!s_memb[ib+2]){ ull kk = KEY(mv.z, ib+2); if (kk > fk) fk = kk; }
                    if (!s_memb[ib+3]){ ull kk = KEY(mv.w, ib+3); if (kk > fk) fk = kk; }
                }
#pragma unroll
                for (int off = 1; off < 64; off <<= 1){
                    ull o = shflxor64(fk, off);
                    if (o > fk) fk = o;
                }
                wk = fk; didFB = 1;
            }
        }
        if (!skip){
            const int wh = KIDX(wk);
            const float wv = KVAL(wk);
            int m0=(sh0==wh), m1=(sh1==wh), m2=(sh2==wh), m3=(sh3==wh);
            ull memMask = __ballot(m0 | m1 | m2 | m3);
            if (memMask != 0ull){
                int fflag = 0, jsl = -1;
#define DSL(i) if (m##i){ int nup = t - ss##i - 1; float te = th_lazy2(st##i, 150.f, 400.f, nup); \
                  if (wv > te){ fflag = 1; sm##i = 0.f; \
                      st##i = fminf(fmaxf(__fadd_rn(__fsub_rn(te,0.05f),5.0f),150.f),400.f); ss##i = t; \
                      jsl = (i << 6) | lane; } }
                DSL(0) DSL(1) DSL(2) DSL(3)
#undef DSL
                ull fm = __ballot(fflag);
                if (fm != 0ull){ if (fflag) j1s[t] = jsl; }
                else if (lane == 0) j1s[t] = -1;
            } else {
                float te_b;
                if (!didFB){
                    float te_s = 0.f; int prop = 0;
                    if (nm0 && i0 == wh){ te_s = cA0.z; prop = 1; }
                    if (nm1 && i1 == wh){ te_s = cA1.z; prop = 1; }
                    if (nm2 && i2 == wh){ te_s = cA2.z; prop = 1; }
                    ull pm = __ballot(prop);
                    if (pm != 0ull){
                        int pl = __ffsll((long long)pm) - 1;
                        te_b = __shfl(te_s, pl);
                    } else {
                        te_b = th_lazy2(thr1[wh], 150.f, 400.f, t);
                    }
                } else {
                    te_b = th_lazy2(thr1[wh], 150.f, 400.f, t);
                }
                int fire = (wv > te_b) ? 1 : 0;
                if (fire){
                    float thnew = fminf(fmaxf(__fadd_rn(__fsub_rn(te_b,0.05f),5.0f),150.f),400.f);
                    if (lane == (nR & 63)){
                        const float4* crow = (const float4*)(c1T + (size_t)wh * Tt);
                        int g1 = (g + 1 < 64) ? g + 1 : 63;
                        int srg = nR >> 6;
#define JN(i) { sh##i = wh; sm##i = 0.f; st##i = thnew; ss##i = t; sr##i = (float)(t+1); \
                dA##i = crow[g]; dB##i = crow[g1]; }
                        if (srg == 0){ JN(0) } else if (srg == 1){ JN(1) }
                        else if (srg == 2){ JN(2) } else { JN(3) }
#undef JN
                        j1s[t] = nR;
                        mh[nR] = wh;
                    }
                    if (lane == 0) s_memb[wh] = 1;
                    nR++;
                } else {
                    if (lane == 0) j1s[t] = -1;
                }
            }
        } else {
            if (lane == 0) j1s[t] = -1;
        }
        // member-drive rotation every 4 steps
        if (jj == 3 && g < 63){
            int g2 = (g + 2 < 64) ? g + 2 : 63;
#define RT(i) { dA##i = dB##i; if (sh##i >= 0) dB##i = ((const float4*)(c1T + (size_t)sh##i * Tt))[g2]; }
            RT(0) RT(1) RT(2) RT(3)
#undef RT
        }
        // candidate rotation + prefetch + membership reads for next step
        cA0 = cB0; cA1 = cB1; cA2 = cB2;
        int tn = (t + 2 < Tt) ? t + 2 : Tt - 1;
        cB0 = cand[(size_t)tn * CAP + lane];
        cB1 = cand[(size_t)tn * CAP + 64 + lane];
        cB2 = cand[(size_t)tn * CAP + 128 + lane];
        mb0 = s_memb[__float_as_int(cA0.y) & 8191];
        mb1 = s_memb[__float_as_int(cA1.y) & 8191];
        mb2 = s_memb[__float_as_int(cA2.y) & 8191];
    }
#define WB(i) if (sh##i >= 0){ r1pre[sh##i] = sr##i; o_r1[sh##i] = sr##i; }
    WB(0) WB(1) WB(2) WB(3)
#undef WB
    if (lane == 0) *nRout = nR;
}

// ---------------- k_colg: gather distinct member columns of W2 ----------------
__global__ __launch_bounds__(256) void k_colg(const float* __restrict__ W2,
        const int* __restrict__ mh, const int* __restrict__ nRout,
        float* __restrict__ colv){
    int slot = blockIdx.x;
    if (slot >= *nRout) return;
    int h = mh[slot];
    int tid = threadIdx.x;
    float* dst = colv + (size_t)slot * Nn;
    for (int n = tid; n < Nn; n += 256) dst[n] = W2[(size_t)n * Hn + h];
}

// ---------------- k_lif2: layer 2 per-neuron LIF, ballot spike masks ----------------
__global__ __launch_bounds__(64) void k_lif2(const float* __restrict__ colv,
        const int* __restrict__ j1s, const float* __restrict__ thr2,
        float* __restrict__ o_r2, ull* __restrict__ spkb, unsigned* __restrict__ anyv){
    __shared__ int s_j[Tt];
    int lane = threadIdx.x, blk = blockIdx.x;
    for (int i = lane; i < Tt; i += 64) s_j[i] = j1s[i];
    __syncthreads();
    int n = blk * 64 + lane;
    float tv = thr2[n], m = 0.f, rp = 0.f;
    for (int t = 0; t < Tt; ++t){
        int s = s_j[t];
        float u = (s >= 0) ? colv[(size_t)s * Nn + n] : 0.f;
        m = __fadd_rn(__fmul_rn(0.8f, m), u);
        int f = 0;
        if (m > tv){
            m = __fsub_rn(m, tv);
            if (rp == 0.f) rp = (float)(t + 1);
            f = 1;
        }
        ull mask = __ballot(f);
        if (lane == 0){
            spkb[t * 64 + blk] = mask;
            if (mask) atomicOr(&anyv[t], 1u);
        }
    }
    o_r2[n] = (rp == 0.f) ? 256.f : rp;
}

// ---------------- k_w3t: W3T[n][c] = W3[c][n] ----------------
__global__ __launch_bounds__(256) void k_w3t(const float* __restrict__ W3,
                                             float* __restrict__ W3T){
    __shared__ float tl[64][65];
    int bx = blockIdx.x & 63, by = blockIdx.x >> 6;
    int n0 = bx * 64, c0 = by * 64;
    int tid = threadIdx.x;
    for (int e = tid; e < 64 * 64; e += 256){
        int r = e >> 6, cc = e & 63;
        tl[r][cc] = W3[(size_t)(c0 + r) * Nn + n0 + cc];
    }
    __syncthreads();
    for (int e = tid; e < 64 * 64; e += 256){
        int rn = e >> 6, cc = e & 63;
        W3T[(size_t)(n0 + rn) * Cn + c0 + cc] = tl[cc][rn];
    }
}

// ---------------- k_sim3: layer 3 WTA; skips exact-zero quiet steps ----------------
__global__ __launch_bounds__(128, 1) void k_sim3(const ull* __restrict__ spkb,
        const unsigned* __restrict__ anyv, const float* __restrict__ W3T,
        const float* __restrict__ thr3, float* __restrict__ o_r3){
    int tid = threadIdx.x, lane = tid & 63, w = tid >> 6;
    __shared__ unsigned s_any[Tt];
    __shared__ ull s_r2[2];
    __shared__ int s_fire;
    for (int i = tid; i < Tt; i += 128) s_any[i] = anyv[i];
    float m = 0.f, th0 = thr3[tid], rp = 0.f, thv = 0.f;
    int ts = -1, zero = 1;
    __syncthreads();
    for (int t = 0; t < Tt; ++t){
        if (zero && s_any[t] == 0u) continue;
        float d = 0.f;
        if (s_any[t]){
            for (int ww = 0; ww < 64; ++ww){
                ull bits = spkb[t * 64 + ww];
                while (bits){
                    int b2 = __ffsll((long long)bits) - 1;
                    bits &= bits - 1;
                    d = __fadd_rn(d, W3T[(size_t)(ww * 64 + b2) * Cn + tid]);
                }
            }
        }
        m = __fadd_rn(__fmul_rn(0.9f, m), d);
        ull k = KEY(m, tid);
#pragma unroll
        for (int off = 32; off >= 1; off >>= 1){
            ull o = __shfl_down(k, off);
            if (o > k) k = o;
        }
        if (lane == 0) s_r2[w] = k;
        __syncthreads();
        ull wk = s_r2[0] > s_r2[1] ? s_r2[0] : s_r2[1];
        int wc = KIDX(wk);
        float wv = KVAL(wk);
        if (tid == wc){
            float te = (ts < 0) ? th_lazy2(th0, 50.f, 200.f, t)
                                : th_lazy2(thv, 50.f, 200.f, t - ts - 1);
            int f = (wv > te) ? 1 : 0;
            s_fire = f;
            if (f){
                thv = fminf(fmaxf(__fadd_rn(__fsub_rn(te, 0.05f), 5.0f), 50.f), 200.f);
                ts = t;
                if (rp == 0.f) rp = (float)(t + 1);
            }
        }
        __syncthreads();
        if (s_fire){ m = 0.f; zero = 1; }
        else zero = 0;
        __syncthreads();
    }
    o_r3[tid] = (rp == 0.f) ? 256.f : rp;
}

// ---------------- k_scalars: zeta/rho/error + factored exp tables ----------------
__global__ __launch_bounds__(1024) void k_scalars(const float* __restrict__ image,
        const float* __restrict__ r1pre, const float* __restrict__ o_r1,
        const float* __restrict__ o_r2,
        float* __restrict__ zeta, float* __restrict__ rho,
        float* __restrict__ imgt, float* __restrict__ eiP, float* __restrict__ eiM,
        float* __restrict__ Pv, float* __restrict__ Qv,
        float* __restrict__ E2P, float* __restrict__ E2M,
        float* __restrict__ o_err, float* __restrict__ o_es){
    int tid = threadIdx.x;
    for (int h = tid; h < Hn; h += 1024){
        float r1f = o_r1[h];
        float mask = (r1pre[h] != 0.f) ? 1.f : 0.f;
        float z = __fmul_rn(__fmul_rn(__fsub_rn(256.f, r1f), mask), 0.00390625f);
        zeta[h] = z;
        Pv[h] = __expf(r1f * 0.05f) * z;
        Qv[h] = __expf(-r1f * 0.05f) * z;
    }
    float acc = 0.f;
    for (int n = tid; n < Nn; n += 1024){
        float img = __fmul_rn(256.f, image[n]);
        float r2f = o_r2[n];
        float e = __fmul_rn(__fsub_rn(img, __fsub_rn(r2f, 4.0f)), 0.00390625f);
        o_err[n] = e;
        rho[n] = __fadd_rn(__fmul_rn(__fsub_rn(__fsub_rn(r2f, 4.0f), img), 0.00390625f), 0.15f);
        imgt[n] = img;
        eiP[n] = __expf(img * 0.05f);
        eiM[n] = __expf(-img * 0.05f);
        E2P[n] = __expf(r2f * 0.05f);
        E2M[n] = __expf(-r2f * 0.05f);
        acc = __fadd_rn(acc, __fmul_rn(e, e));
    }
    __shared__ float red[16];
    for (int off = 32; off >= 1; off >>= 1) acc += __shfl_down(acc, off);
    int lane = tid & 63, w = tid >> 6;
    if (lane == 0) red[w] = acc;
    __syncthreads();
    if (tid == 0){
        float s = 0.f;
        for (int q = 0; q < 16; ++q) s += red[q];
        *o_es = s;
    }
}

// ---------------- STDP weight updates (factored exp, float4 streams) ----------------
__global__ __launch_bounds__(256) void k_w1new(const float* __restrict__ W1,
        const float* __restrict__ imgt, const float* __restrict__ eiP,
        const float* __restrict__ eiM, const float* __restrict__ r1pre,
        const float* __restrict__ o_r1, float* __restrict__ o_W1){
    int h = blockIdx.x, tid = threadIdx.x;
    float r1f = o_r1[h];
    bool msk = (r1pre[h] != 0.f);
    float a = 0.01f * __expf(-r1f * 0.05f);
    float b = 0.01f * __expf( r1f * 0.05f);
    const float4* src = (const float4*)(W1 + (size_t)h * Nn);
    float4* dst = (float4*)(o_W1 + (size_t)h * Nn);
    const float4* ig = (const float4*)imgt;
    const float4* p4 = (const float4*)eiP;
    const float4* m4 = (const float4*)eiM;
    for (int i = tid; i < Nn / 4; i += 256){
        float4 s = src[i];
        if (msk){
            float4 im = ig[i], pp = p4[i], mm = m4[i];
            s.x += (r1f >= im.x) ? a * pp.x : -(b * mm.x);
            s.y += (r1f >= im.y) ? a * pp.y : -(b * mm.y);
            s.z += (r1f >= im.z) ? a * pp.z : -(b * mm.z);
            s.w += (r1f >= im.w) ? a * pp.w : -(b * mm.w);
        } else {
            s.x += 0.01f; s.y += 0.01f; s.z += 0.01f; s.w += 0.01f;
        }
        dst[i] = s;
    }
}

__global__ __launch_bounds__(256) void k_w2new(const float* __restrict__ W2,
        const float* __restrict__ o_r1, const float* __restrict__ Pv,
        const float* __restrict__ Qv, const float* __restrict__ o_r2,
        const float* __restrict__ rho, float* __restrict__ o_W2){
    int n = blockIdx.x, tid = threadIdx.x;
    float r2f = o_r2[n], rh = rho[n];
    float A = 0.01f * rh * __expf(-r2f * 0.05f);
    float B = 0.01f * rh * __expf( r2f * 0.05f);
    const float4* src = (const float4*)(W2 + (size_t)n * Hn);
    float4* dst = (float4*)(o_W2 + (size_t)n * Hn);
    const float4* r14 = (const float4*)o_r1;
    const float4* p4 = (const float4*)Pv;
    const float4* q4 = (const float4*)Qv;
    for (int i = tid; i < Hn / 4; i += 256){
        float4 s = src[i]; float4 rv = r14[i]; float4 pp = p4[i]; float4 qq = q4[i];
        s.x = clamp01(s.x + ((r2f >= rv.x) ? A * pp.x : -(B * qq.x)));
        s.y = clamp01(s.y + ((r2f >= rv.y) ? A * pp.y : -(B * qq.y)));
        s.z = clamp01(s.z + ((r2f >= rv.z) ? A * pp.z : -(B * qq.z)));
        s.w = clamp01(s.w + ((r2f >= rv.w) ? A * pp.w : -(B * qq.w)));
        dst[i] = s;
    }
}

__global__ __launch_bounds__(256) void k_w3new(const float* __restrict__ W3,
        const float* __restrict__ o_r2, const float* __restrict__ E2P,
        const float* __restrict__ E2M, const float* __restrict__ o_r3,
        float* __restrict__ o_W3){
    int c = blockIdx.x, tid = threadIdx.x;
    float r3f = o_r3[c];
    float a = 0.01f * __expf(-r3f * 0.05f);
    float b = 0.01f * __expf( r3f * 0.05f);
    const float4* src = (const float4*)(W3 + (size_t)c * Nn);
    float4* dst = (float4*)(o_W3 + (size_t)c * Nn);
    const float4* r24 = (const float4*)o_r2;
    const float4* p4 = (const float4*)E2P;
    const float4* m4 = (const float4*)E2M;
    for (int i = tid; i < Nn / 4; i += 256){
        float4 s = src[i]; float4 rv = r24[i]; float4 pp = p4[i]; float4 mm = m4[i];
        s.x += (r3f >= rv.x) ? a * pp.x : -(b * mm.x);
        s.y += (r3f >= rv.y) ? a * pp.y : -(b * mm.y);
        s.z += (r3f >= rv.z) ? a * pp.z : -(b * mm.z);
        s.w += (r3f >= rv.w) ? a * pp.w : -(b * mm.w);
        dst[i] = s;
    }
}

extern "C" void kernel_launch(void* const* d_in, const int* in_sizes, int n_in,
                              void* d_out, int out_size, void* d_ws, size_t ws_size,
                              hipStream_t stream){
    const float* image = (const float*)d_in[0];
    const float* W1   = (const float*)d_in[1];
    const float* W2   = (const float*)d_in[2];
    const float* W3   = (const float*)d_in[3];
    const float* thr1 = (const float*)d_in[4];
    const float* thr2 = (const float*)d_in[5];
    const float* thr3 = (const float*)d_in[6];

    float* out  = (float*)d_out;
    float* o_err = out;                       // [4096]
    float* o_es  = out + 4096;                // [1]
    float* o_r1  = out + 4097;                // [8192]
    float* o_r2  = out + 12289;               // [4096]
    float* o_r3  = out + 16385;               // [128]
    float* o_W1  = out + 16513;               // [8192*4096]
    float* o_W2  = o_W1 + (size_t)Hn * Nn;    // [4096*8192]
    float* o_W3  = o_W2 + (size_t)Nn * Hn;    // [128*4096]

    float* ws = (float*)d_ws;
    float* G_T   = ws;                                  // H*T
    float* c1T   = G_T + (size_t)Hn * Tt;               // H*T
    float* M     = c1T + (size_t)Hn * Tt;               // T*H
    float* W3T   = M + (size_t)Tt * Hn;                 // N*C
    float* colv  = W3T + (size_t)Nn * Cn;               // 256*N
    float4* cand = (float4*)(colv + (size_t)256 * Nn);  // T*CAP float4
    ull* spkb    = (ull*)(cand + (size_t)Tt * CAP);     // T*64 u64
    float* r1pre = (float*)(spkb + (size_t)Tt * 64);    // H
    float* zeta  = r1pre + Hn;                          // H
    float* rho   = zeta + Hn;                           // N
    float* imgt  = rho + Nn;                            // N
    float* eiP   = imgt + Nn;                           // N
    float* eiM   = eiP + Nn;                            // N
    float* Pv    = eiM + Nn;                            // H
    float* Qv    = Pv + Hn;                             // H
    float* E2P   = Qv + Hn;                             // N
    float* E2M   = E2P + Nn;                            // N
    int* boff  = (int*)(E2M + Nn);                      // T+1
    int* sidx  = boff + (Tt + 1);                       // N
    int* j1s   = sidx + Nn;                             // T
    int* mh    = j1s + Tt;                              // 256
    int* nRout = mh + 256;                              // 1
    unsigned* anyv = (unsigned*)(nRout + 1);            // T

    k_prep<<<1, 1024, 0, stream>>>(image, boff, sidx, anyv);
    k_gbuckets<<<Hn / 4, 256, 0, stream>>>(W1, boff, sidx, G_T);
    k_c1M<<<Hn / 32, 256, 0, stream>>>(G_T, c1T, M, r1pre, o_r1);
    k_sel<<<Tt, 256, 0, stream>>>(M, thr1, cand);
    k_wta1<<<1, 64, 0, stream>>>(M, c1T, cand, thr1, r1pre, o_r1, j1s, mh, nRout);
    k_colg<<<256, 256, 0, stream>>>(W2, mh, nRout, colv);
    k_lif2<<<Nn / 64, 64, 0, stream>>>(colv, j1s, thr2, o_r2, spkb, anyv);
    k_w3t<<<128, 256, 0, stream>>>(W3, W3T);
    k_sim3<<<1, 128, 0, stream>>>(spkb, anyv, W3T, thr3, o_r3);
    k_scalars<<<1, 1024, 0, stream>>>(image, r1pre, o_r1, o_r2, zeta, rho,
                                      imgt, eiP, eiM, Pv, Qv, E2P, E2M, o_err, o_es);
    k_w1new<<<Hn, 256, 0, stream>>>(W1, imgt, eiP, eiM, r1pre, o_r1, o_W1);
    k_w2new<<<Nn, 256, 0, stream>>>(W2, o_r1, Pv, Qv, o_r2, rho, o_W2);
    k_w3new<<<Cn, 256, 0, stream>>>(W3, o_r2, E2P, E2M, o_r3, o_W3);
}

// Round 6
// 778.178 us; speedup vs baseline: 1.7940x; 1.0590x over previous
//
#include <hip/hip_runtime.h>
#include <cstdint>
#include <cstddef>

#define Hn 8192
#define Nn 4096
#define Cn 128
#define Tt 256
#define CAP 192

typedef unsigned long long ull;

// th after nup clip-updates (decay -0.05 each) from base b, clamped [lo,hi]
__device__ __forceinline__ float th_lazy2(float b, float lo, float hi, int nup){
    if (nup <= 0) return b;
    float a = fminf(fmaxf(__fsub_rn(b, 0.05f), lo), hi);
    if (nup == 1) return a;
    return fmaxf(__fsub_rn(a, __fmul_rn(0.05f, (float)(nup - 1))), lo);
}

__device__ __forceinline__ float clamp01(float v){
    return fminf(fmaxf(v, 0.f), 1.f);
}

// ---- DPP cross-lane reduce helpers (VALU pipe, no LDS) ----
// ctrl: 0x111=row_shr:1 0x112=row_shr:2 0x114=row_shr:4 0x118=row_shr:8
//       0x142=row_bcast15 0x143=row_bcast31  (gfx9/CDNA encodings)
template<int CTRL>
__device__ __forceinline__ int dpp_i(int x, int old){
    return __builtin_amdgcn_update_dpp(old, x, CTRL, 0xf, 0xf, false);
}

// max over 64 lanes of float (works for any values; identity -FLT_MAX), result uniform
__device__ __forceinline__ float wave_max_f(float v){
    const int NEG = __float_as_int(-3.4e38f);
#define STEPM(C) { float o = __int_as_float(dpp_i<C>(__float_as_int(v), NEG)); v = fmaxf(v, o); }
    STEPM(0x111) STEPM(0x112) STEPM(0x114) STEPM(0x118) STEPM(0x142) STEPM(0x143)
#undef STEPM
    return __int_as_float(__builtin_amdgcn_readlane(__float_as_int(v), 63));
}

// min over 64 lanes of unsigned h with carried float payload te; results uniform
__device__ __forceinline__ void wave_minh_te(unsigned &h, float &te){
#define STEPN(C) { unsigned h2 = (unsigned)dpp_i<C>((int)h, (int)0xFFFFFFFFu); \
                   float t2 = __int_as_float(dpp_i<C>(__float_as_int(te), 0)); \
                   if (h2 < h){ h = h2; te = t2; } }
    STEPN(0x111) STEPN(0x112) STEPN(0x114) STEPN(0x118) STEPN(0x142) STEPN(0x143)
#undef STEPN
    h = (unsigned)__builtin_amdgcn_readlane((int)h, 63);
    te = __int_as_float(__builtin_amdgcn_readlane(__float_as_int(te), 63));
}

// ---------------- k_prep: start buckets + deterministic counting sort (1024 thr) ----------------
__global__ __launch_bounds__(1024) void k_prep(const float* __restrict__ image,
        int* __restrict__ boff, int* __restrict__ sidx, unsigned* __restrict__ anyv){
    __shared__ int s_start[Nn];
    __shared__ int s_c4[4][Tt];
    __shared__ int s_boff[Tt + 1];
    int tid = threadIdx.x;
    for (int i = tid; i < Nn; i += 1024)
        s_start[i] = (int)floorf(__fmul_rn(256.f, image[i]));
    if (tid < Tt) anyv[tid] = 0u;
    __syncthreads();
    int b = tid & 255, q = tid >> 8;
    {
        int c = 0;
        for (int k = 0; k < 1024; ++k) c += (s_start[q * 1024 + k] == b) ? 1 : 0;
        s_c4[q][b] = c;
    }
    __syncthreads();
    if (tid == 0){
        int acc = 0;
        for (int bb = 0; bb < Tt; ++bb){
            s_boff[bb] = acc;
            acc += s_c4[0][bb] + s_c4[1][bb] + s_c4[2][bb] + s_c4[3][bb];
        }
        s_boff[Tt] = acc;
    }
    __syncthreads();
    if (tid <= Tt) boff[tid] = s_boff[tid];
    int p = s_boff[b];
    if (q > 0) p += s_c4[0][b];
    if (q > 1) p += s_c4[1][b];
    if (q > 2) p += s_c4[2][b];
    for (int k = 0; k < 1024; ++k){
        int i = q * 1024 + k;
        if (s_start[i] == b) sidx[p++] = i;
    }
}

// ---------------- k_gbuckets: G_T[h][t] = sum_{i in bucket t} W1[h][i] ----------------
__global__ __launch_bounds__(256) void k_gbuckets(const float* __restrict__ W1,
        const int* __restrict__ boff, const int* __restrict__ sidx,
        float* __restrict__ G_T){
    __shared__ float rows[4][Nn]; // 64 KB
    int tid = threadIdx.x;
    int h0 = blockIdx.x * 4;
    for (int r = 0; r < 4; ++r){
        const float4* src = (const float4*)(W1 + (size_t)(h0 + r) * Nn);
        float4* dst = (float4*)rows[r];
        for (int j = tid; j < Nn / 4; j += 256) dst[j] = src[j];
    }
    __syncthreads();
    int t = tid;
    int b0 = boff[t], b1 = boff[t + 1];
    float s0 = 0.f, s1 = 0.f, s2 = 0.f, s3 = 0.f;
    for (int k = b0; k < b1; ++k){
        int i = sidx[k];
        s0 += rows[0][i]; s1 += rows[1][i]; s2 += rows[2][i]; s3 += rows[3][i];
    }
    G_T[(size_t)(h0 + 0) * Tt + t] = s0;
    G_T[(size_t)(h0 + 1) * Tt + t] = s1;
    G_T[(size_t)(h0 + 2) * Tt + t] = s2;
    G_T[(size_t)(h0 + 3) * Tt + t] = s3;
}

// ---------------- k_c1M: fused window-sum + M-scan + c1T transpose + r1 init ----------------
__global__ __launch_bounds__(256) void k_c1M(const float* __restrict__ G_T,
        float* __restrict__ c1T, float* __restrict__ M,
        float* __restrict__ r1pre, float* __restrict__ o_r1){
    __shared__ float tile[32][Tt + 1];
    __shared__ float c1s[32][Tt + 1];
    const int tid = threadIdx.x;
    const int h0 = blockIdx.x * 32;
    for (int r = 0; r < 32; ++r) tile[r][tid] = G_T[(size_t)(h0 + r) * Tt + tid];
    __syncthreads();
    {
        int hs = tid & 31, ts = tid >> 5;
        for (int tb = 0; tb < 32; ++tb){
            int t = tb * 8 + ts;
            int lo = (t - 7 < 0) ? 0 : t - 7;
            float s = 0.f;
            for (int u = lo; u <= t; ++u) s += tile[hs][u];
            c1s[hs][t] = s;
        }
    }
    __syncthreads();
    if (tid < 32){
        float m = 0.f;
        for (int t = 0; t < Tt; ++t){
            m = __fadd_rn(__fmul_rn(0.9f, m), c1s[tid][t]);
            M[(size_t)t * Hn + h0 + tid] = m;
        }
        r1pre[h0 + tid] = 0.f;
        o_r1[h0 + tid] = 256.f;
    }
    {
        int hr = tid >> 3, qq = tid & 7;
        float* drow = c1T + (size_t)(h0 + hr) * Tt + qq * 32;
        for (int k = 0; k < 8; ++k){
            float4 v = make_float4(c1s[hr][qq*32 + 4*k], c1s[hr][qq*32 + 4*k + 1],
                                   c1s[hr][qq*32 + 4*k + 2], c1s[hr][qq*32 + 4*k + 3]);
            ((float4*)drow)[k] = v;
        }
    }
}

// ---------------- k_sel: exact rank-CAP radix-select + candidate list with th ----------------
__global__ __launch_bounds__(256) void k_sel(const float* __restrict__ M,
        const float* __restrict__ thr1, float4* __restrict__ cand){
    const int t = blockIdx.x, tid = threadIdx.x;
    __shared__ float s_row[Hn];        // 32 KB
    __shared__ unsigned s_hist[256];
    __shared__ unsigned s_suf[256];
    __shared__ unsigned s_pref;
    __shared__ int s_rank;
    __shared__ int s_cnt;
    __shared__ int s_idx[CAP + 64];
    {
        const float4* src = (const float4*)(M + (size_t)t * Hn);
        float4* d4 = (float4*)s_row;
        for (int j = tid; j < Hn / 4; j += 256) d4[j] = src[j];
    }
    if (tid == 0){ s_pref = 0u; s_rank = CAP; s_cnt = 0; }
    __syncthreads();
#pragma unroll
    for (int b = 3; b >= 0; --b){
        s_hist[tid] = 0u;
        __syncthreads();
        unsigned pref = s_pref;
        int r = s_rank;
        for (int k = 0; k < 32; ++k){
            unsigned u = __float_as_uint(s_row[tid + (k << 8)]);
            bool match = (b == 3) ? true : ((u >> ((b + 1) * 8)) == pref);
            if (match) atomicAdd(&s_hist[(u >> (b * 8)) & 255], 1u);
        }
        __syncthreads();
        s_suf[tid] = s_hist[tid];
        __syncthreads();
#pragma unroll
        for (int off = 1; off < 256; off <<= 1){
            unsigned v = (tid + off < 256) ? s_suf[tid + off] : 0u;
            __syncthreads();
            s_suf[tid] += v;
            __syncthreads();
        }
        unsigned above = s_suf[tid] - s_hist[tid];
        if ((int)above < r && r <= (int)s_suf[tid]){
            s_pref = (pref << 8) | (unsigned)tid;
            s_rank = r - (int)above;
        }
        __syncthreads();
    }
    unsigned V = s_pref;
    for (int k = 0; k < 32; ++k){
        int i = tid + (k << 8);
        unsigned u = __float_as_uint(s_row[i]);
        if (u >= V){
            int p = atomicAdd(&s_cnt, 1);
            if (p < CAP + 64) s_idx[p] = i;
        }
    }
    __syncthreads();
    int c = s_cnt;
    bool ovf = (c > CAP);
    float vV = __uint_as_float(V);
    for (int i = tid; i < CAP; i += 256){
        float4 e;
        if (ovf){
            e = make_float4(-2.f, 0.f, 0.f, 3.4e38f);
        } else if (i < c){
            int ix = s_idx[i];
            e = make_float4(s_row[ix], __int_as_float(ix),
                            th_lazy2(thr1[ix], 150.f, 400.f, t), vV);
        } else {
            e = make_float4(-1.f, 0.f, 0.f, vV);
        }
        cand[(size_t)t * CAP + i] = e;
    }
}

// ---------------- k_wta1: single-wave serial WTA; DPP reduce, LDS membership ----------------
__global__ __launch_bounds__(64, 1) void k_wta1(
        const float* __restrict__ M, const float* __restrict__ c1T,
        const float4* __restrict__ cand, const float* __restrict__ thr1,
        float* __restrict__ r1pre, float* __restrict__ o_r1,
        int* __restrict__ j1s, int* __restrict__ mh, int* __restrict__ nRout){
    const int lane = threadIdx.x;
    __shared__ unsigned char s_memb[Hn];   // 8 KB
    {
        uint4 z = make_uint4(0u, 0u, 0u, 0u);
        uint4* p = (uint4*)s_memb;
        for (int i = lane; i < Hn / 16; i += 64) p[i] = z;
    }
    int   sh0=-1,sh1=-1,sh2=-1,sh3=-1;
    float sm0=0.f,sm1=0.f,sm2=0.f,sm3=0.f;
    float st0=0.f,st1=0.f,st2=0.f,st3=0.f;
    int   ss0=0,ss1=0,ss2=0,ss3=0;
    float sr0=0.f,sr1=0.f,sr2=0.f,sr3=0.f;
    float4 z4 = make_float4(0.f,0.f,0.f,0.f);
    float4 dA0=z4,dA1=z4,dA2=z4,dA3=z4,dB0=z4,dB1=z4,dB2=z4,dB3=z4;
    int nR = 0;

    // depth-3 candidate prefetch
    float4 cA0 = cand[lane],              cA1 = cand[64 + lane],           cA2 = cand[128 + lane];
    float4 cB0 = cand[CAP + lane],        cB1 = cand[CAP + 64 + lane],     cB2 = cand[CAP + 128 + lane];
    float4 cC0 = cand[2*CAP + lane],      cC1 = cand[2*CAP + 64 + lane],   cC2 = cand[2*CAP + 128 + lane];
    int mb0 = 0, mb1 = 0, mb2 = 0;        // membership flags for current step's candidates

    for (int t = 0; t < Tt; ++t){
        const int g = t >> 2, jj = t & 3;
        // [1] member update + local best
        float bv = -3.4e38f; int bh = 0x7FFFFFFF; float bte = 1e30f;
#define UPD(i) if (sh##i >= 0){ \
            float dv = (jj==0)?dA##i.x:(jj==1)?dA##i.y:(jj==2)?dA##i.z:dA##i.w; \
            sm##i = __fadd_rn(__fmul_rn(0.9f, sm##i), dv); \
            if (sm##i > bv || (sm##i == bv && sh##i < bh)){ bv = sm##i; bh = sh##i; bte = 1e30f; } }
        UPD(0) UPD(1) UPD(2) UPD(3)
#undef UPD
        // [2] candidates (non-member, valid)
        const int i0 = __float_as_int(cA0.y), i1 = __float_as_int(cA1.y), i2 = __float_as_int(cA2.y);
        const int nm0 = (cA0.x >= 0.f) && !mb0;
        const int nm1 = (cA1.x >= 0.f) && !mb1;
        const int nm2 = (cA2.x >= 0.f) && !mb2;
        if (nm0 && (cA0.x > bv || (cA0.x == bv && i0 < bh))){ bv = cA0.x; bh = i0; bte = cA0.z; }
        if (nm1 && (cA1.x > bv || (cA1.x == bv && i1 < bh))){ bv = cA1.x; bh = i1; bte = cA1.z; }
        if (nm2 && (cA2.x > bv || (cA2.x == bv && i2 < bh))){ bv = cA2.x; bh = i2; bte = cA2.z; }
        ull anyNM = __ballot(nm0 | nm1 | nm2);
        // [3][4] DPP argmax (value desc, index asc) with carried te
        float wv = wave_max_f(bv);
        unsigned hp = (bv == wv) ? (unsigned)bh : 0xFFFFFFFFu;
        float tp = bte;
        wave_minh_te(hp, tp);
        int wh = (int)hp;
        float te_min = tp;
        // [5] issue membership reads for next step's candidates (stale wrt this step's join)
        const int ib0 = __float_as_int(cB0.y) & 8191;
        const int ib1 = __float_as_int(cB1.y) & 8191;
        const int ib2 = __float_as_int(cB2.y) & 8191;
        int nb0 = s_memb[ib0], nb1 = s_memb[ib1], nb2 = s_memb[ib2];
        // guards
        int didFB = 0, skip = 0;
        if (anyNM == 0ull){
            float v192 = cA0.w;
            if (wv >= v192){
                // best member dominates all unlisted non-members: exact
            } else if (t > 0 && v192 < 150.f){
                skip = 1;
            } else {
                // rare exact fallback: full-row scan over non-members (+ member slots)
                float fv = -3.4e38f; int fh = 0x7FFFFFFF;
#define RES(i) if (sh##i >= 0 && (sm##i > fv || (sm##i == fv && sh##i < fh))){ fv = sm##i; fh = sh##i; }
                RES(0) RES(1) RES(2) RES(3)
#undef RES
                const float4* Mrow4 = (const float4*)(M + (size_t)t * Hn);
                for (int q = 0; q < 32; ++q){
                    int e = q * 64 + lane;
                    float4 mv = Mrow4[e];
                    int ib = e * 4;
                    if (!s_memb[ib+0] && (mv.x > fv || (mv.x == fv && ib+0 < fh))){ fv = mv.x; fh = ib+0; }
                    if (!s_memb[ib+1] && (mv.y > fv || (mv.y == fv && ib+1 < fh))){ fv = mv.y; fh = ib+1; }
                    if (!s_memb[ib+2] && (mv.z > fv || (mv.z == fv && ib+2 < fh))){ fv = mv.z; fh = ib+2; }
                    if (!s_memb[ib+3] && (mv.w > fv || (mv.w == fv && ib+3 < fh))){ fv = mv.w; fh = ib+3; }
                }
                wv = wave_max_f(fv);
                unsigned h2 = (fv == wv) ? (unsigned)fh : 0xFFFFFFFFu;
                float t2 = 0.f;
                wave_minh_te(h2, t2);
                wh = (int)h2;
                didFB = 1;
            }
        }
        // [6] decision
        int joined = 0;
        if (!skip){
            int m0=(sh0==wh), m1=(sh1==wh), m2=(sh2==wh), m3=(sh3==wh);
            ull memMask = __ballot(m0 | m1 | m2 | m3);
            if (memMask != 0ull){
                int fflag = 0, jsl = -1;
#define DSL(i) if (m##i){ int nup = t - ss##i - 1; float te = th_lazy2(st##i, 150.f, 400.f, nup); \
                  if (wv > te){ fflag = 1; sm##i = 0.f; \
                      st##i = fminf(fmaxf(__fadd_rn(__fsub_rn(te,0.05f),5.0f),150.f),400.f); ss##i = t; \
                      jsl = (i << 6) | lane; } }
                DSL(0) DSL(1) DSL(2) DSL(3)
#undef DSL
                ull fm = __ballot(fflag);
                if (fm != 0ull){ if (fflag) j1s[t] = jsl; }
                else if (lane == 0) j1s[t] = -1;
            } else {
                float te_b = didFB ? th_lazy2(thr1[wh], 150.f, 400.f, t) : te_min;
                int fire = (wv > te_b) ? 1 : 0;
                if (fire){
                    joined = 1;
                    float thnew = fminf(fmaxf(__fadd_rn(__fsub_rn(te_b,0.05f),5.0f),150.f),400.f);
                    if (lane == (nR & 63)){
                        const float4* crow = (const float4*)(c1T + (size_t)wh * Tt);
                        int g1 = (g + 1 < 64) ? g + 1 : 63;
                        int srg = nR >> 6;
#define JN(i) { sh##i = wh; sm##i = 0.f; st##i = thnew; ss##i = t; sr##i = (float)(t+1); \
                dA##i = crow[g]; dB##i = crow[g1]; }
                        if (srg == 0){ JN(0) } else if (srg == 1){ JN(1) }
                        else if (srg == 2){ JN(2) } else { JN(3) }
#undef JN
                        j1s[t] = nR;
                        mh[nR] = wh;
                    }
                    if (lane == 0) s_memb[wh] = 1;
                    nR++;
                } else {
                    if (lane == 0) j1s[t] = -1;
                }
            }
        } else {
            if (lane == 0) j1s[t] = -1;
        }
        // [7] rotations
        if (jj == 3 && g < 63){
            int g2 = (g + 2 < 64) ? g + 2 : 63;
#define RT(i) { dA##i = dB##i; if (sh##i >= 0) dB##i = ((const float4*)(c1T + (size_t)sh##i * Tt))[g2]; }
            RT(0) RT(1) RT(2) RT(3)
#undef RT
        }
        mb0 = nb0 | (joined & (ib0 == wh));
        mb1 = nb1 | (joined & (ib1 == wh));
        mb2 = nb2 | (joined & (ib2 == wh));
        cA0 = cB0; cA1 = cB1; cA2 = cB2;
        cB0 = cC0; cB1 = cC1; cB2 = cC2;
        int tn = (t + 3 < Tt) ? t + 3 : Tt - 1;
        cC0 = cand[(size_t)tn * CAP + lane];
        cC1 = cand[(size_t)tn * CAP + 64 + lane];
        cC2 = cand[(size_t)tn * CAP + 128 + lane];
    }
#define WB(i) if (sh##i >= 0){ r1pre[sh##i] = sr##i; o_r1[sh##i] = sr##i; }
    WB(0) WB(1) WB(2) WB(3)
#undef WB
    if (lane == 0) *nRout = nR;
}

// ---------------- k_colg: gather distinct member columns of W2 ----------------
__global__ __launch_bounds__(256) void k_colg(const float* __restrict__ W2,
        const int* __restrict__ mh, const int* __restrict__ nRout,
        float* __restrict__ colv){
    int slot = blockIdx.x;
    if (slot >= *nRout) return;
    int h = mh[slot];
    int tid = threadIdx.x;
    float* dst = colv + (size_t)slot * Nn;
    for (int n = tid; n < Nn; n += 256) dst[n] = W2[(size_t)n * Hn + h];
}

// ---------------- k_lif2: layer 2 per-neuron LIF, ballot spike masks ----------------
__global__ __launch_bounds__(64) void k_lif2(const float* __restrict__ colv,
        const int* __restrict__ j1s, const float* __restrict__ thr2,
        float* __restrict__ o_r2, ull* __restrict__ spkb, unsigned* __restrict__ anyv){
    __shared__ int s_j[Tt];
    int lane = threadIdx.x, blk = blockIdx.x;
    for (int i = lane; i < Tt; i += 64) s_j[i] = j1s[i];
    __syncthreads();
    int n = blk * 64 + lane;
    float tv = thr2[n], m = 0.f, rp = 0.f;
    for (int t = 0; t < Tt; ++t){
        int s = s_j[t];
        float u = (s >= 0) ? colv[(size_t)s * Nn + n] : 0.f;
        m = __fadd_rn(__fmul_rn(0.8f, m), u);
        int f = 0;
        if (m > tv){
            m = __fsub_rn(m, tv);
            if (rp == 0.f) rp = (float)(t + 1);
            f = 1;
        }
        ull mask = __ballot(f);
        if (lane == 0){
            spkb[t * 64 + blk] = mask;
            if (mask) atomicOr(&anyv[t], 1u);
        }
    }
    o_r2[n] = (rp == 0.f) ? 256.f : rp;
}

// ---------------- k_w3t: W3T[n][c] = W3[c][n] ----------------
__global__ __launch_bounds__(256) void k_w3t(const float* __restrict__ W3,
                                             float* __restrict__ W3T){
    __shared__ float tl[64][65];
    int bx = blockIdx.x & 63, by = blockIdx.x >> 6;
    int n0 = bx * 64, c0 = by * 64;
    int tid = threadIdx.x;
    for (int e = tid; e < 64 * 64; e += 256){
        int r = e >> 6, cc = e & 63;
        tl[r][cc] = W3[(size_t)(c0 + r) * Nn + n0 + cc];
    }
    __syncthreads();
    for (int e = tid; e < 64 * 64; e += 256){
        int rn = e >> 6, cc = e & 63;
        W3T[(size_t)(n0 + rn) * Cn + c0 + cc] = tl[cc][rn];
    }
}

// ---------------- k_sim3: layer 3 WTA; skips exact-zero quiet steps ----------------
__global__ __launch_bounds__(128, 1) void k_sim3(const ull* __restrict__ spkb,
        const unsigned* __restrict__ anyv, const float* __restrict__ W3T,
        const float* __restrict__ thr3, float* __restrict__ o_r3){
    int tid = threadIdx.x, lane = tid & 63, w = tid >> 6;
    __shared__ unsigned s_any[Tt];
    __shared__ ull s_r2[2];
    __shared__ int s_fire;
    for (int i = tid; i < Tt; i += 128) s_any[i] = anyv[i];
    float m = 0.f, th0 = thr3[tid], rp = 0.f, thv = 0.f;
    int ts = -1, zero = 1;
    __syncthreads();
    for (int t = 0; t < Tt; ++t){
        if (zero && s_any[t] == 0u) continue;
        float d = 0.f;
        if (s_any[t]){
            for (int ww = 0; ww < 64; ++ww){
                ull bits = spkb[t * 64 + ww];
                while (bits){
                    int b2 = __ffsll((long long)bits) - 1;
                    bits &= bits - 1;
                    d = __fadd_rn(d, W3T[(size_t)(ww * 64 + b2) * Cn + tid]);
                }
            }
        }
        m = __fadd_rn(__fmul_rn(0.9f, m), d);
        ull k = (((ull)__float_as_uint(m >= 0.f ? m : 0.f)) << 32) | (unsigned)(8191 - tid);
        if (!(m >= 0.f)) k = (unsigned)(8191 - tid);
#pragma unroll
        for (int off = 32; off >= 1; off >>= 1){
            ull o = __shfl_down(k, off);
            if (o > k) k = o;
        }
        if (lane == 0) s_r2[w] = k;
        __syncthreads();
        ull wk = s_r2[0] > s_r2[1] ? s_r2[0] : s_r2[1];
        int wc = 8191 - (int)(wk & 0xFFFFu);
        float wv = __uint_as_float((unsigned)(wk >> 32));
        if (tid == wc){
            float te = (ts < 0) ? th_lazy2(th0, 50.f, 200.f, t)
                                : th_lazy2(thv, 50.f, 200.f, t - ts - 1);
            int f = (wv > te) ? 1 : 0;
            s_fire = f;
            if (f){
                thv = fminf(fmaxf(__fadd_rn(__fsub_rn(te, 0.05f), 5.0f), 50.f), 200.f);
                ts = t;
                if (rp == 0.f) rp = (float)(t + 1);
            }
        }
        __syncthreads();
        if (s_fire){ m = 0.f; zero = 1; }
        else zero = 0;
        __syncthreads();
    }
    o_r3[tid] = (rp == 0.f) ? 256.f : rp;
}

// ---------------- k_scalars: zeta/rho/error + factored exp tables ----------------
__global__ __launch_bounds__(1024) void k_scalars(const float* __restrict__ image,
        const float* __restrict__ r1pre, const float* __restrict__ o_r1,
        const float* __restrict__ o_r2,
        float* __restrict__ zeta, float* __restrict__ rho,
        float* __restrict__ imgt, float* __restrict__ eiP, float* __restrict__ eiM,
        float* __restrict__ Pv, float* __restrict__ Qv,
        float* __restrict__ E2P, float* __restrict__ E2M,
        float* __restrict__ o_err, float* __restrict__ o_es){
    int tid = threadIdx.x;
    for (int h = tid; h < Hn; h += 1024){
        float r1f = o_r1[h];
        float mask = (r1pre[h] != 0.f) ? 1.f : 0.f;
        float z = __fmul_rn(__fmul_rn(__fsub_rn(256.f, r1f), mask), 0.00390625f);
        zeta[h] = z;
        Pv[h] = __expf(r1f * 0.05f) * z;
        Qv[h] = __expf(-r1f * 0.05f) * z;
    }
    float acc = 0.f;
    for (int n = tid; n < Nn; n += 1024){
        float img = __fmul_rn(256.f, image[n]);
        float r2f = o_r2[n];
        float e = __fmul_rn(__fsub_rn(img, __fsub_rn(r2f, 4.0f)), 0.00390625f);
        o_err[n] = e;
        rho[n] = __fadd_rn(__fmul_rn(__fsub_rn(__fsub_rn(r2f, 4.0f), img), 0.00390625f), 0.15f);
        imgt[n] = img;
        eiP[n] = __expf(img * 0.05f);
        eiM[n] = __expf(-img * 0.05f);
        E2P[n] = __expf(r2f * 0.05f);
        E2M[n] = __expf(-r2f * 0.05f);
        acc = __fadd_rn(acc, __fmul_rn(e, e));
    }
    __shared__ float red[16];
    for (int off = 32; off >= 1; off >>= 1) acc += __shfl_down(acc, off);
    int lane = tid & 63, w = tid >> 6;
    if (lane == 0) red[w] = acc;
    __syncthreads();
    if (tid == 0){
        float s = 0.f;
        for (int q = 0; q < 16; ++q) s += red[q];
        *o_es = s;
    }
}

// ---------------- STDP weight updates (factored exp, float4 streams) ----------------
__global__ __launch_bounds__(256) void k_w1new(const float* __restrict__ W1,
        const float* __restrict__ imgt, const float* __restrict__ eiP,
        const float* __restrict__ eiM, const float* __restrict__ r1pre,
        const float* __restrict__ o_r1, float* __restrict__ o_W1){
    int h = blockIdx.x, tid = threadIdx.x;
    float r1f = o_r1[h];
    bool msk = (r1pre[h] != 0.f);
    float a = 0.01f * __expf(-r1f * 0.05f);
    float b = 0.01f * __expf( r1f * 0.05f);
    const float4* src = (const float4*)(W1 + (size_t)h * Nn);
    float4* dst = (float4*)(o_W1 + (size_t)h * Nn);
    const float4* ig = (const float4*)imgt;
    const float4* p4 = (const float4*)eiP;
    const float4* m4 = (const float4*)eiM;
    for (int i = tid; i < Nn / 4; i += 256){
        float4 s = src[i];
        if (msk){
            float4 im = ig[i], pp = p4[i], mm = m4[i];
            s.x += (r1f >= im.x) ? a * pp.x : -(b * mm.x);
            s.y += (r1f >= im.y) ? a * pp.y : -(b * mm.y);
            s.z += (r1f >= im.z) ? a * pp.z : -(b * mm.z);
            s.w += (r1f >= im.w) ? a * pp.w : -(b * mm.w);
        } else {
            s.x += 0.01f; s.y += 0.01f; s.z += 0.01f; s.w += 0.01f;
        }
        dst[i] = s;
    }
}

__global__ __launch_bounds__(256) void k_w2new(const float* __restrict__ W2,
        const float* __restrict__ o_r1, const float* __restrict__ Pv,
        const float* __restrict__ Qv, const float* __restrict__ o_r2,
        const float* __restrict__ rho, float* __restrict__ o_W2){
    int n = blockIdx.x, tid = threadIdx.x;
    float r2f = o_r2[n], rh = rho[n];
    float A = 0.01f * rh * __expf(-r2f * 0.05f);
    float B = 0.01f * rh * __expf( r2f * 0.05f);
    const float4* src = (const float4*)(W2 + (size_t)n * Hn);
    float4* dst = (float4*)(o_W2 + (size_t)n * Hn);
    const float4* r14 = (const float4*)o_r1;
    const float4* p4 = (const float4*)Pv;
    const float4* q4 = (const float4*)Qv;
    for (int i = tid; i < Hn / 4; i += 256){
        float4 s = src[i]; float4 rv = r14[i]; float4 pp = p4[i]; float4 qq = q4[i];
        s.x = clamp01(s.x + ((r2f >= rv.x) ? A * pp.x : -(B * qq.x)));
        s.y = clamp01(s.y + ((r2f >= rv.y) ? A * pp.y : -(B * qq.y)));
        s.z = clamp01(s.z + ((r2f >= rv.z) ? A * pp.z : -(B * qq.z)));
        s.w = clamp01(s.w + ((r2f >= rv.w) ? A * pp.w : -(B * qq.w)));
        dst[i] = s;
    }
}

__global__ __launch_bounds__(256) void k_w3new(const float* __restrict__ W3,
        const float* __restrict__ o_r2, const float* __restrict__ E2P,
        const float* __restrict__ E2M, const float* __restrict__ o_r3,
        float* __restrict__ o_W3){
    int c = blockIdx.x, tid = threadIdx.x;
    float r3f = o_r3[c];
    float a = 0.01f * __expf(-r3f * 0.05f);
    float b = 0.01f * __expf( r3f * 0.05f);
    const float4* src = (const float4*)(W3 + (size_t)c * Nn);
    float4* dst = (float4*)(o_W3 + (size_t)c * Nn);
    const float4* r24 = (const float4*)o_r2;
    const float4* p4 = (const float4*)E2P;
    const float4* m4 = (const float4*)E2M;
    for (int i = tid; i < Nn / 4; i += 256){
        float4 s = src[i]; float4 rv = r24[i]; float4 pp = p4[i]; float4 mm = m4[i];
        s.x += (r3f >= rv.x) ? a * pp.x : -(b * mm.x);
        s.y += (r3f >= rv.y) ? a * pp.y : -(b * mm.y);
        s.z += (r3f >= rv.z) ? a * pp.z : -(b * mm.z);
        s.w += (r3f >= rv.w) ? a * pp.w : -(b * mm.w);
        dst[i] = s;
    }
}

extern "C" void kernel_launch(void* const* d_in, const int* in_sizes, int n_in,
                              void* d_out, int out_size, void* d_ws, size_t ws_size,
                              hipStream_t stream){
    const float* image = (const float*)d_in[0];
    const float* W1   = (const float*)d_in[1];
    const float* W2   = (const float*)d_in[2];
    const float* W3   = (const float*)d_in[3];
    const float* thr1 = (const float*)d_in[4];
    const float* thr2 = (const float*)d_in[5];
    const float* thr3 = (const float*)d_in[6];

    float* out  = (float*)d_out;
    float* o_err = out;                       // [4096]
    float* o_es  = out + 4096;                // [1]
    float* o_r1  = out + 4097;                // [8192]
    float* o_r2  = out + 12289;               // [4096]
    float* o_r3  = out + 16385;               // [128]
    float* o_W1  = out + 16513;               // [8192*4096]
    float* o_W2  = o_W1 + (size_t)Hn * Nn;    // [4096*8192]
    float* o_W3  = o_W2 + (size_t)Nn * Hn;    // [128*4096]

    float* ws = (float*)d_ws;
    float* G_T   = ws;                                  // H*T
    float* c1T   = G_T + (size_t)Hn * Tt;               // H*T
    float* M     = c1T + (size_t)Hn * Tt;               // T*H
    float* W3T   = M + (size_t)Tt * Hn;                 // N*C
    float* colv  = W3T + (size_t)Nn * Cn;               // 256*N
    float4* cand = (float4*)(colv + (size_t)256 * Nn);  // T*CAP float4
    ull* spkb    = (ull*)(cand + (size_t)Tt * CAP);     // T*64 u64
    float* r1pre = (float*)(spkb + (size_t)Tt * 64);    // H
    float* zeta  = r1pre + Hn;                          // H
    float* rho   = zeta + Hn;                           // N
    float* imgt  = rho + Nn;                            // N
    float* eiP   = imgt + Nn;                           // N
    float* eiM   = eiP + Nn;                            // N
    float* Pv    = eiM + Nn;                            // H
    float* Qv    = Pv + Hn;                             // H
    float* E2P   = Qv + Hn;                             // N
    float* E2M   = E2P + Nn;                            // N
    int* boff  = (int*)(E2M + Nn);                      // T+1
    int* sidx  = boff + (Tt + 1);                       // N
    int* j1s   = sidx + Nn;                             // T
    int* mh    = j1s + Tt;                              // 256
    int* nRout = mh + 256;                              // 1
    unsigned* anyv = (unsigned*)(nRout + 1);            // T

    k_prep<<<1, 1024, 0, stream>>>(image, boff, sidx, anyv);
    k_gbuckets<<<Hn / 4, 256, 0, stream>>>(W1, boff, sidx, G_T);
    k_c1M<<<Hn / 32, 256, 0, stream>>>(G_T, c1T, M, r1pre, o_r1);
    k_sel<<<Tt, 256, 0, stream>>>(M, thr1, cand);
    k_wta1<<<1, 64, 0, stream>>>(M, c1T, cand, thr1, r1pre, o_r1, j1s, mh, nRout);
    k_colg<<<256, 256, 0, stream>>>(W2, mh, nRout, colv);
    k_lif2<<<Nn / 64, 64, 0, stream>>>(colv, j1s, thr2, o_r2, spkb, anyv);
    k_w3t<<<128, 256, 0, stream>>>(W3, W3T);
    k_sim3<<<1, 128, 0, stream>>>(spkb, anyv, W3T, thr3, o_r3);
    k_scalars<<<1, 1024, 0, stream>>>(image, r1pre, o_r1, o_r2, zeta, rho,
                                      imgt, eiP, eiM, Pv, Qv, E2P, E2M, o_err, o_es);
    k_w1new<<<Hn, 256, 0, stream>>>(W1, imgt, eiP, eiM, r1pre, o_r1, o_W1);
    k_w2new<<<Nn, 256, 0, stream>>>(W2, o_r1, Pv, Qv, o_r2, rho, o_W2);
    k_w3new<<<Cn, 256, 0, stream>>>(W3, o_r2, E2P, E2M, o_r3, o_W3);
}